// Round 2
// baseline (1096.864 us; speedup 1.0000x reference)
//
#include <hip/hip_runtime.h>
#include <hip/hip_bf16.h>

__device__ __forceinline__ float lrelu(float x){ return x >= 0.f ? x : 0.2f*x; }
__device__ __forceinline__ float sigm(float x){ return 1.f/(1.f+__expf(-x)); }

// ---------------- workspace layout (float offsets) ----------------
static constexpr size_t OFF_X0    = 0;          // 89*4096 = 364544
static constexpr size_t OFF_POS   = 475712;     // 16384  [h][i][d]
static constexpr size_t OFF_WQT   = 492096;     // 12288  [s][c][o]
static constexpr size_t OFF_STATS = 504384;     // 4*768
static constexpr size_t OFF_P1    = 507456;     // 89*64*1024
static constexpr size_t OFF_P2    = 6340160;    // 89*64*256
static constexpr size_t OFF_FEAT  = 7798336;    // 89*64*256
static constexpr size_t OFF_MH1   = 9256512;    // 89*64*256
static constexpr size_t OFF_RES   = 10714688;   // 89*64*256
static constexpr size_t OFF_MU    = 12172864;   // 320
static constexpr size_t OFF_COV   = 12173184;   // 5*64*64
static constexpr size_t OFF_SIM   = 12193664;   // 64*5*256
static constexpr size_t OFF_R1    = 12275584;   // big overlaid region (23,330,816)
static constexpr size_t OFF_C1    = OFF_R1;                 // 89*64*4096 (stage 1 only)
static constexpr size_t OFF_C2    = OFF_R1;                 // 89*64*1024 (c1 dead)
static constexpr size_t OFF_C3    = OFF_R1 + 5832704;       // 89*64*256
static constexpr size_t OFF_F3    = OFF_R1 + 7290880;
static constexpr size_t OFF_C4    = OFF_R1 + 8749056;
static constexpr size_t OFF_QKV   = OFF_R1 + 10207232;      // 89*3*256*64
static constexpr size_t OFF_MHRAW = OFF_R1 + 14581760;      // 89*64*256
static constexpr size_t OFF_XCA   = OFF_R1 + 16039936;
static constexpr size_t OFF_SFB   = OFF_R1 + 17498112;      // 89*2*256
static constexpr size_t OFF_QN    = OFF_R1 + 17543680;      // 64*64*256

// ---------------- prep: pack inputs + pos + W^T ----------------
__global__ __launch_bounds__(256) void prep_k(const float* __restrict__ in1, const float* __restrict__ in2,
        const float* __restrict__ relh, const float* __restrict__ relw,
        const float* __restrict__ wq, const float* __restrict__ wk, const float* __restrict__ wv,
        float* __restrict__ ws)
{
    int idx = blockIdx.x*256 + threadIdx.x;
    if (idx < 364544) { ws[OFF_X0+idx] = (idx < 262144 ? in1[idx] : in2[idx-262144]); return; }
    idx -= 364544;
    if (idx < 16384) {
        const int h = idx>>12, r = idx&4095, i = r>>4, d = r&15;
        ws[OFF_POS+idx] = relh[h*256 + d*16 + (i&15)] + relw[h*256 + d*16 + (i>>4)];
        return;
    }
    idx -= 16384;
    if (idx < 12288) {
        const int s = idx/4096, r = idx%4096, c = r>>6, o = r&63;
        const float* wp = (s==0)?wq:((s==1)?wk:wv);
        ws[OFF_WQT+idx] = wp[o*64 + c];   // [s][c][o] = W[o][c]
    }
}

// ---------------- direct 3x3 conv, LDS input staging ----------------
template<int H, int W, int CIN, int CH, int OCB, int PT>
__global__ __launch_bounds__(256) void conv3x3_k(const float* __restrict__ in,
                                                 const float* __restrict__ wt,
                                                 float* __restrict__ out)
{
    constexpr int P = W + 1;
    constexpr int PLANE = H * P;
    constexpr int HW = H * W;
    constexpr int PASSES = HW / (256 * PT);
    __shared__ float lds[CH * PLANE];
    const int img = blockIdx.x;
    const int och0 = blockIdx.y * OCB;
    const int t = threadIdx.x;

    float acc[PASSES][OCB][PT];
#pragma unroll
    for (int a=0;a<PASSES;a++)
#pragma unroll
      for (int o=0;o<OCB;o++)
#pragma unroll
        for (int p=0;p<PT;p++) acc[a][o][p]=0.f;

    for (int cc0 = 0; cc0 < CIN; cc0 += CH) {
        __syncthreads();
        for (int idx = t; idx < CH*HW; idx += 256) {
            const int c = idx / HW, p = idx % HW;
            lds[c*PLANE + (p/W)*P + (p%W)] = in[((size_t)img*CIN + cc0 + c)*HW + p];
        }
        __syncthreads();
        for (int c = 0; c < CH; ++c) {
            float wr[OCB][9];
#pragma unroll
            for (int o=0;o<OCB;o++)
#pragma unroll
              for (int k=0;k<9;k++)
                wr[o][k] = wt[((size_t)(och0+o)*CIN + (cc0+c))*9 + k];   // wave-uniform -> s_load
            const float* Lc = lds + c*PLANE;
#pragma unroll
            for (int ps=0; ps<PASSES; ++ps) {
                const int px0 = (ps*256 + t)*PT;
                const int y = px0 / W, x0 = px0 % W;
#pragma unroll
                for (int ky=0; ky<3; ++ky) {
                    const int yy = y + ky - 1;
                    if (yy >= 0 && yy < H) {
                        const float* Lr = Lc + yy*P;
                        float r[PT+2];
                        r[0] = (x0 > 0) ? Lr[x0-1] : 0.f;
#pragma unroll
                        for (int k2=0;k2<PT;k2++) r[k2+1] = Lr[x0+k2];
                        r[PT+1] = (x0+PT < W) ? Lr[x0+PT] : 0.f;
#pragma unroll
                        for (int p=0;p<PT;p++)
#pragma unroll
                          for (int kx=0;kx<3;kx++) {
                              const float v = r[p+kx];
#pragma unroll
                              for (int o=0;o<OCB;o++)
                                  acc[ps][o][p] += v * wr[o][ky*3+kx];
                          }
                    }
                }
            }
        }
    }
#pragma unroll
    for (int ps=0; ps<PASSES; ++ps) {
        const int px0 = (ps*256 + t)*PT;
#pragma unroll
        for (int o=0;o<OCB;o++)
#pragma unroll
          for (int p=0;p<PT;p++)
            out[((size_t)img*64 + och0+o)*HW + px0 + p] = acc[ps][o][p];
    }
}

// ---------------- group-wise BN stats (6 groups: query=64, 5 classes x 5 shots) ----------------
__device__ __forceinline__ int bn_group(int img){ return (img < 64) ? 0 : (1 + (img-64)/5); }

template<int HW>
__global__ __launch_bounds__(256) void bnstats_k(const float* __restrict__ in, float* __restrict__ stats)
{
    __shared__ float r1[256], r2[256];
    const int g = blockIdx.x, c = blockIdx.y, t = threadIdx.x;
    const int cnt  = (g==0)?64:5;
    const int base = (g==0)?0:(64 + (g-1)*5);
    float s=0.f, ss=0.f;
    for (int ii=0; ii<cnt; ++ii) {
        const float* pl = in + ((size_t)(base+ii)*64 + c)*HW;
        for (int p=t; p<HW; p+=256) { const float v = pl[p]; s += v; ss += v*v; }
    }
    r1[t]=s; r2[t]=ss; __syncthreads();
    for (int st=128; st>0; st>>=1){ if(t<st){ r1[t]+=r1[t+st]; r2[t]+=r2[t+st]; } __syncthreads(); }
    if (t==0) {
        const float n = (float)(cnt*HW);
        const float m = r1[0]/n;
        const float var = fmaxf(r2[0]/n - m*m, 0.f);
        stats[(g*64+c)*2]   = m;
        stats[(g*64+c)*2+1] = 1.f/sqrtf(var + 1e-5f);
    }
}

template<int H, int W>
__global__ __launch_bounds__(256) void bnpool_k(const float* __restrict__ in, const float* __restrict__ stats,
                                 const float* __restrict__ gw, const float* __restrict__ bw,
                                 float* __restrict__ out)
{
    const int img = blockIdx.x, c = blockIdx.y, t = threadIdx.x;
    const int g = bn_group(img);
    const float m = stats[(g*64+c)*2], istd = stats[(g*64+c)*2+1];
    const float a = gw[c]*istd;
    const float b = bw[c] - m*a;
    constexpr int W2=W/2, HW=H*W, N2=(H/2)*W2;
    const float* pl = in + ((size_t)img*64 + c)*HW;
    float* po = out + ((size_t)img*64 + c)*N2;
    for (int opx=t; opx<N2; opx+=256) {
        const int oy=opx/W2, ox=opx%W2;
        const float* q = pl + (2*oy)*W + 2*ox;
        const float v0=lrelu(a*q[0]+b), v1=lrelu(a*q[1]+b), v2=lrelu(a*q[W]+b), v3=lrelu(a*q[W+1]+b);
        po[opx] = fmaxf(fmaxf(v0,v1),fmaxf(v2,v3));
    }
}

__global__ __launch_bounds__(256) void bnapply256_k(const float* __restrict__ in, const float* __restrict__ stats,
                                 const float* __restrict__ gw, const float* __restrict__ bw,
                                 float* __restrict__ out)
{
    const int img = blockIdx.x, c = blockIdx.y, t = threadIdx.x;
    const int g = bn_group(img);
    const float m = stats[(g*64+c)*2], istd = stats[(g*64+c)*2+1];
    const float a = gw[c]*istd;
    const float b = bw[c] - m*a;
    const size_t base = ((size_t)img*64 + c)*256;
    out[base+t] = lrelu(a*in[base+t]+b);
}

// ---------------- MHSA: q/k/v projection (per image, per matrix) ----------------
__global__ __launch_bounds__(256) void proj_k(const float* __restrict__ feat, const float* __restrict__ wT,
               const float* __restrict__ bq, const float* __restrict__ bk, const float* __restrict__ bv,
               float* __restrict__ qkv)
{
    __shared__ float xl[64*256];   // 64 KB exactly
    const int img = blockIdx.x, s = blockIdx.y, t = threadIdx.x;
    for (int idx=t; idx<16384; idx+=256) xl[idx] = feat[(size_t)img*16384 + idx];
    const float* bias = (s==0)?bq:((s==1)?bk:bv);
    const float* wp = wT + s*4096;      // [c][o]
    const int o0 = (t>>4)*4, i0 = (t&15)*16;
    __syncthreads();
    float acc[4][16];
    float b0[4];
#pragma unroll
    for (int o=0;o<4;o++) b0[o]=bias[o0+o];
#pragma unroll
    for (int o=0;o<4;o++)
#pragma unroll
      for (int i=0;i<16;i++) acc[o][i]=b0[o];
    for (int c=0;c<64;c++){
        const float4 w4 = *(const float4*)(wp + c*64 + o0);
        const float* xr = xl + c*256 + i0;
#pragma unroll
        for (int k=0;k<4;k++){
            const float4 x4 = *(const float4*)(xr + 4*k);
            acc[0][4*k+0]+=w4.x*x4.x; acc[0][4*k+1]+=w4.x*x4.y; acc[0][4*k+2]+=w4.x*x4.z; acc[0][4*k+3]+=w4.x*x4.w;
            acc[1][4*k+0]+=w4.y*x4.x; acc[1][4*k+1]+=w4.y*x4.y; acc[1][4*k+2]+=w4.y*x4.z; acc[1][4*k+3]+=w4.y*x4.w;
            acc[2][4*k+0]+=w4.z*x4.x; acc[2][4*k+1]+=w4.z*x4.y; acc[2][4*k+2]+=w4.z*x4.z; acc[2][4*k+3]+=w4.z*x4.w;
            acc[3][4*k+0]+=w4.w*x4.x; acc[3][4*k+1]+=w4.w*x4.y; acc[3][4*k+2]+=w4.w*x4.z; acc[3][4*k+3]+=w4.w*x4.w;
        }
    }
#pragma unroll
    for (int ii=0;ii<16;ii++){
        const float4 v = make_float4(acc[0][ii],acc[1][ii],acc[2][ii],acc[3][ii]);
        *(float4*)(qkv + ((size_t)(img*3+s)*256 + i0+ii)*64 + o0) = v;
    }
}

// ---------------- attention: two-pass softmax, score = q_i.k_j + pos_i.q_j ----------------
__global__ __launch_bounds__(256) void attn_k(const float* __restrict__ qkv, const float* __restrict__ pos,
                               float* __restrict__ mhraw)
{
    __shared__ float qT[4096], kT[4096], vT[4096];  // [j][d] layouts, 48 KB
    const int img = blockIdx.x, h = blockIdx.y, t = threadIdx.x;
    const float* base = qkv + (size_t)img*3*16384;
    for (int idx=t; idx<4096; idx+=256){
        const int i = idx>>4, d = idx&15;
        const int col = h*16+d;
        qT[idx] = base[(size_t)i*64 + col];
        kT[idx] = base[16384 + (size_t)i*64 + col];
        vT[idx] = base[32768 + (size_t)i*64 + col];
    }
    __syncthreads();
    const int i = t;
    float qreg[16], preg[16];
#pragma unroll
    for (int k=0;k<4;k++){
        *(float4*)&qreg[4*k] = *(const float4*)&qT[i*16+4*k];
        *(float4*)&preg[4*k] = *(const float4*)(pos + h*4096 + i*16 + 4*k);
    }
    float mx = -1e30f;
    for (int j=0;j<256;j++){
        float s=0.f;
#pragma unroll
        for (int d=0;d<16;d++) s += qreg[d]*kT[j*16+d] + preg[d]*qT[j*16+d];
        mx = fmaxf(mx, s);
    }
    float l = 0.f;
    float accv[16];
#pragma unroll
    for (int d=0;d<16;d++) accv[d]=0.f;
    for (int j=0;j<256;j++){
        float s=0.f;
#pragma unroll
        for (int d=0;d<16;d++) s += qreg[d]*kT[j*16+d] + preg[d]*qT[j*16+d];
        const float e = __expf(s - mx);
        l += e;
#pragma unroll
        for (int d=0;d<16;d++) accv[d] += e*vT[j*16+d];
    }
    const float rl = 1.f/l;
#pragma unroll
    for (int d=0;d<16;d++)
        mhraw[((size_t)img*64 + h*16 + d)*256 + i] = accv[d]*rl;
}

// ---------------- mhsa per-sample norm + ln affine + residual ----------------
__global__ __launch_bounds__(256) void mhnorm_k(const float* __restrict__ mhraw, const float* __restrict__ lng,
                  const float* __restrict__ lnb, const float* __restrict__ feat, float* __restrict__ out)
{
    __shared__ float r1[256], r2[256];
    const int img = blockIdx.x, t = threadIdx.x;
    const float* base = mhraw + (size_t)img*16384;
    float s=0.f, ss=0.f;
    for (int idx=t; idx<16384; idx+=256){ const float v=base[idx]; s+=v; ss+=v*v; }
    r1[t]=s; r2[t]=ss; __syncthreads();
    for (int st=128;st>0;st>>=1){ if(t<st){r1[t]+=r1[t+st]; r2[t]+=r2[t+st];} __syncthreads(); }
    const float m = r1[0]/16384.f;
    const float var = fmaxf(r2[0]/16384.f - m*m, 0.f);
    const float istd = 1.f/sqrtf(var+1e-5f);
    for (int idx=t; idx<16384; idx+=256){
        const float v = (base[idx]-m)*istd*lng[idx] + lnb[idx] + feat[(size_t)img*16384+idx];
        out[(size_t)img*16384+idx]=v;
    }
}

// ---------------- CBAM channel attention + spatial stats ----------------
__global__ __launch_bounds__(256) void cbamchan_k(const float* __restrict__ feat,
        const float* __restrict__ w1, const float* __restrict__ b1,
        const float* __restrict__ w2, const float* __restrict__ b2,
        float* __restrict__ xca, float* __restrict__ sfb)
{
    __shared__ float pa[256], pm[256];
    __shared__ float favg[64], fmx[64], z1s[8], ca[64];
    const int img = blockIdx.x, t = threadIdx.x;
    const float* base = feat + (size_t)img*16384;
    {
        const int c = t>>2, part = t&3;
        const float* p = base + c*256 + part*64;
        float s=0.f, mx=-1e30f;
        for (int k=0;k<64;k++){ const float v=p[k]; s+=v; mx=fmaxf(mx,v); }
        pa[t]=s; pm[t]=mx;
    }
    __syncthreads();
    if (t<64){
        favg[t] = (pa[t*4]+pa[t*4+1]+pa[t*4+2]+pa[t*4+3])/256.f;
        fmx[t]  = fmaxf(fmaxf(pm[t*4],pm[t*4+1]),fmaxf(pm[t*4+2],pm[t*4+3]));
    }
    __syncthreads();
    if (t<8){
        const int which = t>>2, o = t&3;
        const float* f = which? fmx : favg;
        float z = b1[o];
        for (int c=0;c<64;c++) z += w1[o*64+c]*f[c];
        z1s[t] = fmaxf(z, 0.f);
    }
    __syncthreads();
    if (t<64){
        float z = 2.f*b2[t];   // exc(avg)+exc(max) carries 2x cb2
#pragma unroll
        for (int k=0;k<4;k++) z += w2[t*4+k]*(z1s[k]+z1s[4+k]);
        ca[t] = sigm(z);
    }
    __syncthreads();
    {
        const int i = t;
        float s=0.f, mx=-1e30f;
        for (int c=0;c<64;c++){
            const float v = ca[c]*base[c*256+i];
            xca[(size_t)img*16384 + c*256 + i] = v;
            s += v; mx = fmaxf(mx, v);
        }
        sfb[(size_t)img*512 + i]       = s/64.f;
        sfb[(size_t)img*512 + 256 + i] = mx;
    }
}

// ---------------- CBAM spatial 7x7 + final sa_module sum ----------------
__global__ __launch_bounds__(256) void cbamsp_k(const float* __restrict__ sfb,
      const float* __restrict__ sw, const float* __restrict__ sb,
      const float* __restrict__ mh1, const float* __restrict__ xca, const float* __restrict__ feat,
      float* __restrict__ res)
{
    __shared__ float sf[512];
    __shared__ float wl[98];
    const int img = blockIdx.x, t = threadIdx.x;
    for (int idx=t; idx<512; idx+=256) sf[idx] = sfb[(size_t)img*512 + idx];
    if (t<98) wl[t] = sw[t];
    __syncthreads();
    const int i = t, y = i>>4, x = i&15;
    float s = sb[0];
    for (int ch=0; ch<2; ++ch)
      for (int ky=0; ky<7; ++ky){
        const int yy = y+ky-3;
        if (yy<0||yy>=16) continue;
        for (int kx=0; kx<7; ++kx){
            const int xx = x+kx-3;
            if (xx<0||xx>=16) continue;
            s += sf[ch*256 + yy*16 + xx]*wl[ch*49 + ky*7 + kx];
        }
      }
    const float sa = sigm(s);
    const size_t b = (size_t)img*16384;
    for (int c=0;c<64;c++){
        const size_t idx = b + c*256 + i;
        res[idx] = mh1[idx] + sa*xca[idx] + feat[idx];   // mh1 already contains +x
    }
}

// ---------------- covariance ----------------
__global__ __launch_bounds__(256) void covmu_k(const float* __restrict__ res, float* __restrict__ mu)
{
    __shared__ float r1[256];
    const int n = blockIdx.x, c = blockIdx.y, t = threadIdx.x;
    float s=0.f;
    for (int sh=0; sh<5; ++sh)
        s += res[((size_t)(64 + n*5 + sh)*64 + c)*256 + t];
    r1[t]=s; __syncthreads();
    for (int st=128;st>0;st>>=1){ if(t<st) r1[t]+=r1[t+st]; __syncthreads(); }
    if (t==0) mu[n*64+c] = r1[0]/1280.f;
}

__global__ __launch_bounds__(256) void cov_k(const float* __restrict__ res, const float* __restrict__ mu,
                                             float* __restrict__ cov)
{
    __shared__ float Xl[64*129];   // 33 KB
    const int n = blockIdx.x, by = blockIdx.y, t = threadIdx.x;
    const int c = by*16 + (t>>4);
    const int d0 = (t&15)*4;
    float acc[4] = {0.f,0.f,0.f,0.f};
    for (int sh=0; sh<5; ++sh)
      for (int half=0; half<2; ++half){
        __syncthreads();
        for (int idx=t; idx<8192; idx+=256){
            const int ch = idx>>7, p = idx&127;
            Xl[ch*129+p] = res[((size_t)(64+n*5+sh)*64 + ch)*256 + half*128 + p] - mu[n*64+ch];
        }
        __syncthreads();
        for (int p=0;p<128;p++){
            const float xc = Xl[c*129+p];
#pragma unroll
            for (int k=0;k<4;k++) acc[k] += xc*Xl[(d0+k)*129+p];
        }
      }
#pragma unroll
    for (int k=0;k<4;k++) cov[((size_t)n*64 + c)*64 + d0+k] = acc[k]*(1.f/1279.f);
}

// ---------------- Q normalize over hw per (b,c) ----------------
__global__ __launch_bounds__(64) void qn_k(const float* __restrict__ res, float* __restrict__ qn)
{
    const int b = blockIdx.x, c = blockIdx.y, t = threadIdx.x;
    const size_t base = ((size_t)b*64 + c)*256;
    const float4 v = *(const float4*)(res + base + t*4);
    float ss = v.x*v.x + v.y*v.y + v.z*v.z + v.w*v.w;
#pragma unroll
    for (int off=32; off>0; off>>=1) ss += __shfl_xor(ss, off);
    const float inv = 1.f/sqrtf(ss);
    float4 o; o.x=v.x*inv; o.y=v.y*inv; o.z=v.z*inv; o.w=v.w*inv;
    *(float4*)(qn + base + t*4) = o;
}

// ---------------- sim[b,j,i] = Qn(:,i)^T cov_j Qn(:,i) ----------------
__global__ __launch_bounds__(256) void sim_k(const float* __restrict__ qn, const float* __restrict__ cov,
                                             float* __restrict__ sim)
{
    __shared__ float covj[64*65];
    __shared__ float Vl[64*68];
    __shared__ float simred[320];
    const int b = blockIdx.x, iq = blockIdx.y, t = threadIdx.x;
    const int i0g = iq*64;
    for (int idx=t; idx<4096; idx+=256){
        const int c = idx>>6, il = idx&63;
        Vl[c*68+il] = qn[((size_t)b*64+c)*256 + i0g + il];
    }
    for (int idx=t; idx<320; idx+=256) simred[idx]=0.f;
    const int c0 = (t>>4)*4, i0 = (t&15)*4;
    for (int j=0;j<5;j++){
        __syncthreads();
        for (int idx=t; idx<4096; idx+=256)
            covj[(idx>>6)*65 + (idx&63)] = cov[(size_t)j*4096 + idx];
        __syncthreads();
        float pt[4][4];
#pragma unroll
        for (int a=0;a<4;a++)
#pragma unroll
          for (int bb=0;bb<4;bb++) pt[a][bb]=0.f;
        for (int d=0; d<64; ++d){
            const float4 vv = *(const float4*)&Vl[d*68 + i0];
            float cw[4];
#pragma unroll
            for (int cc=0;cc<4;cc++) cw[cc] = covj[(c0+cc)*65 + d];
#pragma unroll
            for (int cc=0;cc<4;cc++){
                pt[cc][0] += cw[cc]*vv.x;
                pt[cc][1] += cw[cc]*vv.y;
                pt[cc][2] += cw[cc]*vv.z;
                pt[cc][3] += cw[cc]*vv.w;
            }
        }
#pragma unroll
        for (int ii=0;ii<4;ii++){
            float s = 0.f;
#pragma unroll
            for (int cc=0;cc<4;cc++) s += pt[cc][ii]*Vl[(c0+cc)*68 + i0+ii];
            atomicAdd(&simred[j*64 + i0 + ii], s);
        }
    }
    __syncthreads();
    for (int idx=t; idx<320; idx+=256){
        const int j = idx>>6, il = idx&63;
        sim[((size_t)b*5 + j)*256 + i0g + il] = simred[idx];
    }
}

// ---------------- classifier ----------------
__global__ __launch_bounds__(256) void cls_k(const float* __restrict__ sim, const float* __restrict__ cw,
                                             float* __restrict__ out)
{
    __shared__ float red[256];
    const int b = blockIdx.x, t = threadIdx.x;
    const float w = cw[t];
    for (int j=0;j<5;j++){
        const float v = sim[((size_t)b*5 + j)*256 + t];
        red[t] = lrelu(v)*w;
        __syncthreads();
        for (int st=128;st>0;st>>=1){ if(t<st) red[t]+=red[t+st]; __syncthreads(); }
        if (t==0) out[b*5+j] = red[0];
        __syncthreads();
    }
}

// ---------------- launch ----------------
extern "C" void kernel_launch(void* const* d_in, const int* in_sizes, int n_in,
                              void* d_out, int out_size, void* d_ws, size_t ws_size,
                              hipStream_t stream)
{
    const float* IN[31];
    for (int i=0;i<31;i++) IN[i] = (const float*)d_in[i];
    float* W = (float*)d_ws;
    float* OUT = (float*)d_out;

    prep_k<<<1536,256,0,stream>>>(IN[0],IN[1],IN[20],IN[21],IN[14],IN[16],IN[18],W);

    // stage 1: conv1 -> BN/lrelu/pool -> p1 [89,64,32,32]
    conv3x3_k<64,64,1,1,4,4><<<dim3(89,16),256,0,stream>>>(W+OFF_X0, IN[2], W+OFF_C1);
    bnstats_k<4096><<<dim3(6,64),256,0,stream>>>(W+OFF_C1, W+OFF_STATS);
    bnpool_k<64,64><<<dim3(89,64),256,0,stream>>>(W+OFF_C1, W+OFF_STATS, IN[3], IN[4], W+OFF_P1);

    // stage 2: conv2 -> BN/lrelu/pool -> p2 [89,64,16,16]
    conv3x3_k<32,32,64,8,8,4><<<dim3(89,8),256,0,stream>>>(W+OFF_P1, IN[5], W+OFF_C2);
    bnstats_k<1024><<<dim3(6,64),256,0,stream>>>(W+OFF_C2, W+OFF_STATS+768);
    bnpool_k<32,32><<<dim3(89,64),256,0,stream>>>(W+OFF_C2, W+OFF_STATS+768, IN[6], IN[7], W+OFF_P2);

    // stage 3: conv3 -> BN/lrelu -> f3
    conv3x3_k<16,16,64,32,8,1><<<dim3(89,8),256,0,stream>>>(W+OFF_P2, IN[8], W+OFF_C3);
    bnstats_k<256><<<dim3(6,64),256,0,stream>>>(W+OFF_C3, W+OFF_STATS+1536);
    bnapply256_k<<<dim3(89,64),256,0,stream>>>(W+OFF_C3, W+OFF_STATS+1536, IN[9], IN[10], W+OFF_F3);

    // stage 4: conv4 -> BN/lrelu -> feat
    conv3x3_k<16,16,64,32,8,1><<<dim3(89,8),256,0,stream>>>(W+OFF_F3, IN[11], W+OFF_C4);
    bnstats_k<256><<<dim3(6,64),256,0,stream>>>(W+OFF_C4, W+OFF_STATS+2304);
    bnapply256_k<<<dim3(89,64),256,0,stream>>>(W+OFF_C4, W+OFF_STATS+2304, IN[12], IN[13], W+OFF_FEAT);

    // MHSA
    proj_k<<<dim3(89,3),256,0,stream>>>(W+OFF_FEAT, W+OFF_WQT, IN[15], IN[17], IN[19], W+OFF_QKV);
    attn_k<<<dim3(89,4),256,0,stream>>>(W+OFF_QKV, W+OFF_POS, W+OFF_MHRAW);
    mhnorm_k<<<89,256,0,stream>>>(W+OFF_MHRAW, IN[22], IN[23], W+OFF_FEAT, W+OFF_MH1);

    // CBAM + sa_module sum
    cbamchan_k<<<89,256,0,stream>>>(W+OFF_FEAT, IN[24], IN[25], IN[26], IN[27], W+OFF_XCA, W+OFF_SFB);
    cbamsp_k<<<89,256,0,stream>>>(W+OFF_SFB, IN[28], IN[29], W+OFF_MH1, W+OFF_XCA, W+OFF_FEAT, W+OFF_RES);

    // covariance metric + classifier
    covmu_k<<<dim3(5,64),256,0,stream>>>(W+OFF_RES, W+OFF_MU);
    cov_k<<<dim3(5,4),256,0,stream>>>(W+OFF_RES, W+OFF_MU, W+OFF_COV);
    qn_k<<<dim3(64,64),64,0,stream>>>(W+OFF_RES, W+OFF_QN);
    sim_k<<<dim3(64,4),256,0,stream>>>(W+OFF_QN, W+OFF_COV, W+OFF_SIM);
    cls_k<<<64,256,0,stream>>>(W+OFF_SIM, IN[30], OUT);
}

// Round 3
// 818.135 us; speedup vs baseline: 1.3407x; 1.3407x over previous
//
#include <hip/hip_runtime.h>
#include <hip/hip_bf16.h>

__device__ __forceinline__ float lrelu(float x){ return x >= 0.f ? x : 0.2f*x; }
__device__ __forceinline__ float sigm(float x){ return 1.f/(1.f+__expf(-x)); }

// ---------------- workspace layout (float offsets) ----------------
static constexpr size_t OFF_X0    = 0;          // 89*4096 = 364544
static constexpr size_t OFF_POS   = 475712;     // 16384  [h][i][d]
static constexpr size_t OFF_WQT   = 492096;     // 12288  [s][c][o]
static constexpr size_t OFF_STATS = 504384;     // 4 stages * 6 groups * 64 ch * {sum,ss} -> {mean,istd}
static constexpr size_t OFF_P1    = 507456;     // 89*64*1024
static constexpr size_t OFF_P2    = 6340160;    // 89*64*256
static constexpr size_t OFF_FEAT  = 7798336;    // 89*64*256
static constexpr size_t OFF_MH1   = 9256512;    // 89*64*256
static constexpr size_t OFF_RES   = 10714688;   // 89*64*256
static constexpr size_t OFF_MU    = 12172864;   // 320
static constexpr size_t OFF_COV   = 12173184;   // 5*64*64
static constexpr size_t OFF_SIM   = 12193664;   // 64*5*256
static constexpr size_t OFF_R1    = 12275584;   // big overlaid region
static constexpr size_t OFF_C1    = OFF_R1;                 // 89*64*4096 (stage 1 only)
static constexpr size_t OFF_C2    = OFF_R1;                 // 89*64*1024 (c1 dead)
static constexpr size_t OFF_C3    = OFF_R1 + 5832704;       // 89*64*256
static constexpr size_t OFF_F3    = OFF_R1 + 7290880;
static constexpr size_t OFF_C4    = OFF_R1 + 8749056;
static constexpr size_t OFF_QKV   = OFF_R1 + 10207232;      // 89*3*256*64
static constexpr size_t OFF_MHRAW = OFF_R1 + 14581760;      // 89*64*256
static constexpr size_t OFF_XCA   = OFF_R1 + 16039936;
static constexpr size_t OFF_SFB   = OFF_R1 + 17498112;      // 89*2*256
static constexpr size_t OFF_QN    = OFF_R1 + 17543680;      // 64*64*256

__device__ __forceinline__ int bn_group(int img){ return (img < 64) ? 0 : (1 + (img-64)/5); }

// ---------------- prep: pack inputs + pos + W^T + zero BN-sum area ----------------
__global__ __launch_bounds__(256) void prep_k(const float* __restrict__ in1, const float* __restrict__ in2,
        const float* __restrict__ relh, const float* __restrict__ relw,
        const float* __restrict__ wq, const float* __restrict__ wk, const float* __restrict__ wv,
        float* __restrict__ ws)
{
    int idx = blockIdx.x*256 + threadIdx.x;
    if (idx < 364544) { ws[OFF_X0+idx] = (idx < 262144 ? in1[idx] : in2[idx-262144]); return; }
    idx -= 364544;
    if (idx < 16384) {
        const int h = idx>>12, r = idx&4095, i = r>>4, d = r&15;
        ws[OFF_POS+idx] = relh[h*256 + d*16 + (i&15)] + relw[h*256 + d*16 + (i>>4)];
        return;
    }
    idx -= 16384;
    if (idx < 12288) {
        const int s = idx/4096, r = idx%4096, c = r>>6, o = r&63;
        const float* wp = (s==0)?wq:((s==1)?wk:wv);
        ws[OFF_WQT+idx] = wp[o*64 + c];   // [s][c][o] = W[o][c]
        return;
    }
    idx -= 12288;
    if (idx < 3072) ws[OFF_STATS+idx] = 0.f;   // zero all 4 stages' sum/ss slots
}

// ---------------- direct 3x3 conv, LDS input staging, fused BN-sum epilogue ----------------
template<int H, int W, int CIN, int CH, int OCB, int PT>
__global__ __launch_bounds__(256) void conv3x3_k(const float* __restrict__ in,
                                                 const float* __restrict__ wt,
                                                 float* __restrict__ out,
                                                 float* __restrict__ bnsum)
{
    constexpr int P = W + 1;
    constexpr int PLANE = H * P;
    constexpr int HW = H * W;
    constexpr int PASSES = HW / (256 * PT);
    __shared__ float lds[CH * PLANE];
    __shared__ float red1[256], red2[256];
    const int img = blockIdx.x;
    const int och0 = blockIdx.y * OCB;
    const int t = threadIdx.x;

    float acc[PASSES][OCB][PT];
#pragma unroll
    for (int a=0;a<PASSES;a++)
#pragma unroll
      for (int o=0;o<OCB;o++)
#pragma unroll
        for (int p=0;p<PT;p++) acc[a][o][p]=0.f;

    for (int cc0 = 0; cc0 < CIN; cc0 += CH) {
        __syncthreads();
        for (int idx = t; idx < CH*HW; idx += 256) {
            const int c = idx / HW, p = idx % HW;
            lds[c*PLANE + (p/W)*P + (p%W)] = in[((size_t)img*CIN + cc0 + c)*HW + p];
        }
        __syncthreads();
        for (int c = 0; c < CH; ++c) {
            float wr[OCB][9];
#pragma unroll
            for (int o=0;o<OCB;o++)
#pragma unroll
              for (int k=0;k<9;k++)
                wr[o][k] = wt[((size_t)(och0+o)*CIN + (cc0+c))*9 + k];   // wave-uniform -> s_load
            const float* Lc = lds + c*PLANE;
#pragma unroll
            for (int ps=0; ps<PASSES; ++ps) {
                const int px0 = (ps*256 + t)*PT;
                const int y = px0 / W, x0 = px0 % W;
#pragma unroll
                for (int ky=0; ky<3; ++ky) {
                    const int yy = y + ky - 1;
                    if (yy >= 0 && yy < H) {
                        const float* Lr = Lc + yy*P;
                        float r[PT+2];
                        r[0] = (x0 > 0) ? Lr[x0-1] : 0.f;
#pragma unroll
                        for (int k2=0;k2<PT;k2++) r[k2+1] = Lr[x0+k2];
                        r[PT+1] = (x0+PT < W) ? Lr[x0+PT] : 0.f;
#pragma unroll
                        for (int p=0;p<PT;p++)
#pragma unroll
                          for (int kx=0;kx<3;kx++) {
                              const float v = r[p+kx];
#pragma unroll
                              for (int o=0;o<OCB;o++)
                                  acc[ps][o][p] += v * wr[o][ky*3+kx];
                          }
                    }
                }
            }
        }
    }
#pragma unroll
    for (int ps=0; ps<PASSES; ++ps) {
        const int px0 = (ps*256 + t)*PT;
#pragma unroll
        for (int o=0;o<OCB;o++)
#pragma unroll
          for (int p=0;p<PT;p++)
            out[((size_t)img*64 + och0+o)*HW + px0 + p] = acc[ps][o][p];
    }
    // fused group-BN partial sums: block covers ALL HW pixels of (img, och0..och0+OCB)
    const int g = bn_group(img);
#pragma unroll
    for (int o=0;o<OCB;o++){
        float s=0.f, ss=0.f;
#pragma unroll
        for (int ps=0;ps<PASSES;ps++)
#pragma unroll
          for (int p=0;p<PT;p++){ const float v=acc[ps][o][p]; s+=v; ss+=v*v; }
        __syncthreads();
        red1[t]=s; red2[t]=ss;
        __syncthreads();
        for (int st=128;st>0;st>>=1){ if(t<st){ red1[t]+=red1[t+st]; red2[t]+=red2[t+st]; } __syncthreads(); }
        if (t==0){
            atomicAdd(&bnsum[(g*64 + och0+o)*2],   red1[0]);
            atomicAdd(&bnsum[(g*64 + och0+o)*2+1], red2[0]);
        }
    }
}

// ---------------- finalize BN stats in place: (sum,ss) -> (mean, 1/sqrt(var+eps)) ----------------
__global__ __launch_bounds__(384) void bnfin_k(float* __restrict__ s, int HW)
{
    const int t = threadIdx.x;           // t = g*64 + c, 6 groups
    const int g = t>>6;
    const float n = (float)(((g==0)?64:5) * HW);
    const float sum = s[t*2], ss = s[t*2+1];
    const float m = sum/n;
    const float var = fmaxf(ss/n - m*m, 0.f);
    s[t*2]   = m;
    s[t*2+1] = 1.f/sqrtf(var + 1e-5f);
}

template<int H, int W>
__global__ __launch_bounds__(256) void bnpool_k(const float* __restrict__ in, const float* __restrict__ stats,
                                 const float* __restrict__ gw, const float* __restrict__ bw,
                                 float* __restrict__ out)
{
    const int img = blockIdx.x, c = blockIdx.y, t = threadIdx.x;
    const int g = bn_group(img);
    const float m = stats[(g*64+c)*2], istd = stats[(g*64+c)*2+1];
    const float a = gw[c]*istd;
    const float b = bw[c] - m*a;
    constexpr int W2=W/2, HW=H*W, N2=(H/2)*W2;
    const float* pl = in + ((size_t)img*64 + c)*HW;
    float* po = out + ((size_t)img*64 + c)*N2;
    for (int opx=t; opx<N2; opx+=256) {
        const int oy=opx/W2, ox=opx%W2;
        const float* q = pl + (2*oy)*W + 2*ox;
        const float v0=lrelu(a*q[0]+b), v1=lrelu(a*q[1]+b), v2=lrelu(a*q[W]+b), v3=lrelu(a*q[W+1]+b);
        po[opx] = fmaxf(fmaxf(v0,v1),fmaxf(v2,v3));
    }
}

__global__ __launch_bounds__(256) void bnapply256_k(const float* __restrict__ in, const float* __restrict__ stats,
                                 const float* __restrict__ gw, const float* __restrict__ bw,
                                 float* __restrict__ out)
{
    const int img = blockIdx.x, c = blockIdx.y, t = threadIdx.x;
    const int g = bn_group(img);
    const float m = stats[(g*64+c)*2], istd = stats[(g*64+c)*2+1];
    const float a = gw[c]*istd;
    const float b = bw[c] - m*a;
    const size_t base = ((size_t)img*64 + c)*256;
    out[base+t] = lrelu(a*in[base+t]+b);
}

// ---------------- MHSA: q/k/v projection (per image, per matrix) ----------------
__global__ __launch_bounds__(256) void proj_k(const float* __restrict__ feat, const float* __restrict__ wT,
               const float* __restrict__ bq, const float* __restrict__ bk, const float* __restrict__ bv,
               float* __restrict__ qkv)
{
    __shared__ float xl[64*256];   // 64 KB exactly
    const int img = blockIdx.x, s = blockIdx.y, t = threadIdx.x;
    for (int idx=t; idx<16384; idx+=256) xl[idx] = feat[(size_t)img*16384 + idx];
    const float* bias = (s==0)?bq:((s==1)?bk:bv);
    const float* wp = wT + s*4096;      // [c][o]
    const int o0 = (t>>4)*4, i0 = (t&15)*16;
    __syncthreads();
    float acc[4][16];
    float b0[4];
#pragma unroll
    for (int o=0;o<4;o++) b0[o]=bias[o0+o];
#pragma unroll
    for (int o=0;o<4;o++)
#pragma unroll
      for (int i=0;i<16;i++) acc[o][i]=b0[o];
    for (int c=0;c<64;c++){
        const float4 w4 = *(const float4*)(wp + c*64 + o0);
        const float* xr = xl + c*256 + i0;
#pragma unroll
        for (int k=0;k<4;k++){
            const float4 x4 = *(const float4*)(xr + 4*k);
            acc[0][4*k+0]+=w4.x*x4.x; acc[0][4*k+1]+=w4.x*x4.y; acc[0][4*k+2]+=w4.x*x4.z; acc[0][4*k+3]+=w4.x*x4.w;
            acc[1][4*k+0]+=w4.y*x4.x; acc[1][4*k+1]+=w4.y*x4.y; acc[1][4*k+2]+=w4.y*x4.z; acc[1][4*k+3]+=w4.y*x4.w;
            acc[2][4*k+0]+=w4.z*x4.x; acc[2][4*k+1]+=w4.z*x4.y; acc[2][4*k+2]+=w4.z*x4.z; acc[2][4*k+3]+=w4.z*x4.w;
            acc[3][4*k+0]+=w4.w*x4.x; acc[3][4*k+1]+=w4.w*x4.y; acc[3][4*k+2]+=w4.w*x4.z; acc[3][4*k+3]+=w4.w*x4.w;
        }
    }
#pragma unroll
    for (int ii=0;ii<16;ii++){
        const float4 v = make_float4(acc[0][ii],acc[1][ii],acc[2][ii],acc[3][ii]);
        *(float4*)(qkv + ((size_t)(img*3+s)*256 + i0+ii)*64 + o0) = v;
    }
}

// ---------------- attention: two-pass softmax, score = q_i.k_j + pos_i.q_j ----------------
__global__ __launch_bounds__(256) void attn_k(const float* __restrict__ qkv, const float* __restrict__ pos,
                               float* __restrict__ mhraw)
{
    __shared__ float qT[4096], kT[4096], vT[4096];  // [j][d] layouts, 48 KB
    const int img = blockIdx.x, h = blockIdx.y, t = threadIdx.x;
    const float* base = qkv + (size_t)img*3*16384;
    for (int idx=t; idx<4096; idx+=256){
        const int i = idx>>4, d = idx&15;
        const int col = h*16+d;
        qT[idx] = base[(size_t)i*64 + col];
        kT[idx] = base[16384 + (size_t)i*64 + col];
        vT[idx] = base[32768 + (size_t)i*64 + col];
    }
    __syncthreads();
    const int i = t;
    float qreg[16], preg[16];
#pragma unroll
    for (int k=0;k<4;k++){
        *(float4*)&qreg[4*k] = *(const float4*)&qT[i*16+4*k];
        *(float4*)&preg[4*k] = *(const float4*)(pos + h*4096 + i*16 + 4*k);
    }
    float mx = -1e30f;
    for (int j=0;j<256;j++){
        float s=0.f;
#pragma unroll
        for (int d=0;d<16;d++) s += qreg[d]*kT[j*16+d] + preg[d]*qT[j*16+d];
        mx = fmaxf(mx, s);
    }
    float l = 0.f;
    float accv[16];
#pragma unroll
    for (int d=0;d<16;d++) accv[d]=0.f;
    for (int j=0;j<256;j++){
        float s=0.f;
#pragma unroll
        for (int d=0;d<16;d++) s += qreg[d]*kT[j*16+d] + preg[d]*qT[j*16+d];
        const float e = __expf(s - mx);
        l += e;
#pragma unroll
        for (int d=0;d<16;d++) accv[d] += e*vT[j*16+d];
    }
    const float rl = 1.f/l;
#pragma unroll
    for (int d=0;d<16;d++)
        mhraw[((size_t)img*64 + h*16 + d)*256 + i] = accv[d]*rl;
}

// ---------------- mhsa per-sample norm + ln affine + residual ----------------
__global__ __launch_bounds__(256) void mhnorm_k(const float* __restrict__ mhraw, const float* __restrict__ lng,
                  const float* __restrict__ lnb, const float* __restrict__ feat, float* __restrict__ out)
{
    __shared__ float r1[256], r2[256];
    const int img = blockIdx.x, t = threadIdx.x;
    const float* base = mhraw + (size_t)img*16384;
    float s=0.f, ss=0.f;
    for (int idx=t; idx<16384; idx+=256){ const float v=base[idx]; s+=v; ss+=v*v; }
    r1[t]=s; r2[t]=ss; __syncthreads();
    for (int st=128;st>0;st>>=1){ if(t<st){r1[t]+=r1[t+st]; r2[t]+=r2[t+st];} __syncthreads(); }
    const float m = r1[0]/16384.f;
    const float var = fmaxf(r2[0]/16384.f - m*m, 0.f);
    const float istd = 1.f/sqrtf(var+1e-5f);
    for (int idx=t; idx<16384; idx+=256){
        const float v = (base[idx]-m)*istd*lng[idx] + lnb[idx] + feat[(size_t)img*16384+idx];
        out[(size_t)img*16384+idx]=v;
    }
}

// ---------------- CBAM channel attention + spatial stats ----------------
__global__ __launch_bounds__(256) void cbamchan_k(const float* __restrict__ feat,
        const float* __restrict__ w1, const float* __restrict__ b1,
        const float* __restrict__ w2, const float* __restrict__ b2,
        float* __restrict__ xca, float* __restrict__ sfb)
{
    __shared__ float pa[256], pm[256];
    __shared__ float favg[64], fmx[64], z1s[8], ca[64];
    const int img = blockIdx.x, t = threadIdx.x;
    const float* base = feat + (size_t)img*16384;
    {
        const int c = t>>2, part = t&3;
        const float* p = base + c*256 + part*64;
        float s=0.f, mx=-1e30f;
        for (int k=0;k<64;k++){ const float v=p[k]; s+=v; mx=fmaxf(mx,v); }
        pa[t]=s; pm[t]=mx;
    }
    __syncthreads();
    if (t<64){
        favg[t] = (pa[t*4]+pa[t*4+1]+pa[t*4+2]+pa[t*4+3])/256.f;
        fmx[t]  = fmaxf(fmaxf(pm[t*4],pm[t*4+1]),fmaxf(pm[t*4+2],pm[t*4+3]));
    }
    __syncthreads();
    if (t<8){
        const int which = t>>2, o = t&3;
        const float* f = which? fmx : favg;
        float z = b1[o];
        for (int c=0;c<64;c++) z += w1[o*64+c]*f[c];
        z1s[t] = fmaxf(z, 0.f);
    }
    __syncthreads();
    if (t<64){
        float z = 2.f*b2[t];   // exc(avg)+exc(max) carries 2x cb2
#pragma unroll
        for (int k=0;k<4;k++) z += w2[t*4+k]*(z1s[k]+z1s[4+k]);
        ca[t] = sigm(z);
    }
    __syncthreads();
    {
        const int i = t;
        float s=0.f, mx=-1e30f;
        for (int c=0;c<64;c++){
            const float v = ca[c]*base[c*256+i];
            xca[(size_t)img*16384 + c*256 + i] = v;
            s += v; mx = fmaxf(mx, v);
        }
        sfb[(size_t)img*512 + i]       = s/64.f;
        sfb[(size_t)img*512 + 256 + i] = mx;
    }
}

// ---------------- CBAM spatial 7x7 + final sa_module sum ----------------
__global__ __launch_bounds__(256) void cbamsp_k(const float* __restrict__ sfb,
      const float* __restrict__ sw, const float* __restrict__ sb,
      const float* __restrict__ mh1, const float* __restrict__ xca, const float* __restrict__ feat,
      float* __restrict__ res)
{
    __shared__ float sf[512];
    __shared__ float wl[98];
    const int img = blockIdx.x, t = threadIdx.x;
    for (int idx=t; idx<512; idx+=256) sf[idx] = sfb[(size_t)img*512 + idx];
    if (t<98) wl[t] = sw[t];
    __syncthreads();
    const int i = t, y = i>>4, x = i&15;
    float s = sb[0];
    for (int ch=0; ch<2; ++ch)
      for (int ky=0; ky<7; ++ky){
        const int yy = y+ky-3;
        if (yy<0||yy>=16) continue;
        for (int kx=0; kx<7; ++kx){
            const int xx = x+kx-3;
            if (xx<0||xx>=16) continue;
            s += sf[ch*256 + yy*16 + xx]*wl[ch*49 + ky*7 + kx];
        }
      }
    const float sa = sigm(s);
    const size_t b = (size_t)img*16384;
    for (int c=0;c<64;c++){
        const size_t idx = b + c*256 + i;
        res[idx] = mh1[idx] + sa*xca[idx] + feat[idx];   // mh1 already contains +x
    }
}

// ---------------- covariance ----------------
__global__ __launch_bounds__(256) void covmu_k(const float* __restrict__ res, float* __restrict__ mu)
{
    __shared__ float r1[256];
    const int n = blockIdx.x, c = blockIdx.y, t = threadIdx.x;
    float s=0.f;
    for (int sh=0; sh<5; ++sh)
        s += res[((size_t)(64 + n*5 + sh)*64 + c)*256 + t];
    r1[t]=s; __syncthreads();
    for (int st=128;st>0;st>>=1){ if(t<st) r1[t]+=r1[t+st]; __syncthreads(); }
    if (t==0) mu[n*64+c] = r1[0]/1280.f;
}

__global__ __launch_bounds__(256) void cov_k(const float* __restrict__ res, const float* __restrict__ mu,
                                             float* __restrict__ cov)
{
    __shared__ float Xl[64*129];   // 33 KB
    const int n = blockIdx.x, by = blockIdx.y, t = threadIdx.x;
    const int c = by*16 + (t>>4);
    const int d0 = (t&15)*4;
    float acc[4] = {0.f,0.f,0.f,0.f};
    for (int sh=0; sh<5; ++sh)
      for (int half=0; half<2; ++half){
        __syncthreads();
        for (int idx=t; idx<8192; idx+=256){
            const int ch = idx>>7, p = idx&127;
            Xl[ch*129+p] = res[((size_t)(64+n*5+sh)*64 + ch)*256 + half*128 + p] - mu[n*64+ch];
        }
        __syncthreads();
        for (int p=0;p<128;p++){
            const float xc = Xl[c*129+p];
#pragma unroll
            for (int k=0;k<4;k++) acc[k] += xc*Xl[(d0+k)*129+p];
        }
      }
#pragma unroll
    for (int k=0;k<4;k++) cov[((size_t)n*64 + c)*64 + d0+k] = acc[k]*(1.f/1279.f);
}

// ---------------- Q normalize over hw per (b,c) ----------------
__global__ __launch_bounds__(64) void qn_k(const float* __restrict__ res, float* __restrict__ qn)
{
    const int b = blockIdx.x, c = blockIdx.y, t = threadIdx.x;
    const size_t base = ((size_t)b*64 + c)*256;
    const float4 v = *(const float4*)(res + base + t*4);
    float ss = v.x*v.x + v.y*v.y + v.z*v.z + v.w*v.w;
#pragma unroll
    for (int off=32; off>0; off>>=1) ss += __shfl_xor(ss, off);
    const float inv = 1.f/sqrtf(ss);
    float4 o; o.x=v.x*inv; o.y=v.y*inv; o.z=v.z*inv; o.w=v.w*inv;
    *(float4*)(qn + base + t*4) = o;
}

// ---------------- sim[b,j,i] = Qn(:,i)^T cov_j Qn(:,i) ----------------
__global__ __launch_bounds__(256) void sim_k(const float* __restrict__ qn, const float* __restrict__ cov,
                                             float* __restrict__ sim)
{
    __shared__ float covj[64*65];
    __shared__ float Vl[64*68];
    __shared__ float simred[320];
    const int b = blockIdx.x, iq = blockIdx.y, t = threadIdx.x;
    const int i0g = iq*64;
    for (int idx=t; idx<4096; idx+=256){
        const int c = idx>>6, il = idx&63;
        Vl[c*68+il] = qn[((size_t)b*64+c)*256 + i0g + il];
    }
    for (int idx=t; idx<320; idx+=256) simred[idx]=0.f;
    const int c0 = (t>>4)*4, i0 = (t&15)*4;
    for (int j=0;j<5;j++){
        __syncthreads();
        for (int idx=t; idx<4096; idx+=256)
            covj[(idx>>6)*65 + (idx&63)] = cov[(size_t)j*4096 + idx];
        __syncthreads();
        float pt[4][4];
#pragma unroll
        for (int a=0;a<4;a++)
#pragma unroll
          for (int bb=0;bb<4;bb++) pt[a][bb]=0.f;
        for (int d=0; d<64; ++d){
            const float4 vv = *(const float4*)&Vl[d*68 + i0];
            float cw[4];
#pragma unroll
            for (int cc=0;cc<4;cc++) cw[cc] = covj[(c0+cc)*65 + d];
#pragma unroll
            for (int cc=0;cc<4;cc++){
                pt[cc][0] += cw[cc]*vv.x;
                pt[cc][1] += cw[cc]*vv.y;
                pt[cc][2] += cw[cc]*vv.z;
                pt[cc][3] += cw[cc]*vv.w;
            }
        }
#pragma unroll
        for (int ii=0;ii<4;ii++){
            float s = 0.f;
#pragma unroll
            for (int cc=0;cc<4;cc++) s += pt[cc][ii]*Vl[(c0+cc)*68 + i0+ii];
            atomicAdd(&simred[j*64 + i0 + ii], s);
        }
    }
    __syncthreads();
    for (int idx=t; idx<320; idx+=256){
        const int j = idx>>6, il = idx&63;
        sim[((size_t)b*5 + j)*256 + i0g + il] = simred[idx];
    }
}

// ---------------- classifier ----------------
__global__ __launch_bounds__(256) void cls_k(const float* __restrict__ sim, const float* __restrict__ cw,
                                             float* __restrict__ out)
{
    __shared__ float red[256];
    const int b = blockIdx.x, t = threadIdx.x;
    const float w = cw[t];
    for (int j=0;j<5;j++){
        const float v = sim[((size_t)b*5 + j)*256 + t];
        red[t] = lrelu(v)*w;
        __syncthreads();
        for (int st=128;st>0;st>>=1){ if(t<st) red[t]+=red[t+st]; __syncthreads(); }
        if (t==0) out[b*5+j] = red[0];
        __syncthreads();
    }
}

// ---------------- launch ----------------
extern "C" void kernel_launch(void* const* d_in, const int* in_sizes, int n_in,
                              void* d_out, int out_size, void* d_ws, size_t ws_size,
                              hipStream_t stream)
{
    const float* IN[31];
    for (int i=0;i<31;i++) IN[i] = (const float*)d_in[i];
    float* W = (float*)d_ws;
    float* OUT = (float*)d_out;

    prep_k<<<1548,256,0,stream>>>(IN[0],IN[1],IN[20],IN[21],IN[14],IN[16],IN[18],W);

    // stage 1: conv1(+stats) -> finalize -> BN/lrelu/pool -> p1 [89,64,32,32]
    conv3x3_k<64,64,1,1,4,4><<<dim3(89,16),256,0,stream>>>(W+OFF_X0, IN[2], W+OFF_C1, W+OFF_STATS);
    bnfin_k<<<1,384,0,stream>>>(W+OFF_STATS, 4096);
    bnpool_k<64,64><<<dim3(89,64),256,0,stream>>>(W+OFF_C1, W+OFF_STATS, IN[3], IN[4], W+OFF_P1);

    // stage 2: conv2(+stats) -> finalize -> BN/lrelu/pool -> p2 [89,64,16,16]
    conv3x3_k<32,32,64,8,8,4><<<dim3(89,8),256,0,stream>>>(W+OFF_P1, IN[5], W+OFF_C2, W+OFF_STATS+768);
    bnfin_k<<<1,384,0,stream>>>(W+OFF_STATS+768, 1024);
    bnpool_k<32,32><<<dim3(89,64),256,0,stream>>>(W+OFF_C2, W+OFF_STATS+768, IN[6], IN[7], W+OFF_P2);

    // stage 3: conv3(+stats) -> finalize -> BN/lrelu -> f3
    conv3x3_k<16,16,64,32,8,1><<<dim3(89,8),256,0,stream>>>(W+OFF_P2, IN[8], W+OFF_C3, W+OFF_STATS+1536);
    bnfin_k<<<1,384,0,stream>>>(W+OFF_STATS+1536, 256);
    bnapply256_k<<<dim3(89,64),256,0,stream>>>(W+OFF_C3, W+OFF_STATS+1536, IN[9], IN[10], W+OFF_F3);

    // stage 4: conv4(+stats) -> finalize -> BN/lrelu -> feat
    conv3x3_k<16,16,64,32,8,1><<<dim3(89,8),256,0,stream>>>(W+OFF_F3, IN[11], W+OFF_C4, W+OFF_STATS+2304);
    bnfin_k<<<1,384,0,stream>>>(W+OFF_STATS+2304, 256);
    bnapply256_k<<<dim3(89,64),256,0,stream>>>(W+OFF_C4, W+OFF_STATS+2304, IN[12], IN[13], W+OFF_FEAT);

    // MHSA
    proj_k<<<dim3(89,3),256,0,stream>>>(W+OFF_FEAT, W+OFF_WQT, IN[15], IN[17], IN[19], W+OFF_QKV);
    attn_k<<<dim3(89,4),256,0,stream>>>(W+OFF_QKV, W+OFF_POS, W+OFF_MHRAW);
    mhnorm_k<<<89,256,0,stream>>>(W+OFF_MHRAW, IN[22], IN[23], W+OFF_FEAT, W+OFF_MH1);

    // CBAM + sa_module sum
    cbamchan_k<<<89,256,0,stream>>>(W+OFF_FEAT, IN[24], IN[25], IN[26], IN[27], W+OFF_XCA, W+OFF_SFB);
    cbamsp_k<<<89,256,0,stream>>>(W+OFF_SFB, IN[28], IN[29], W+OFF_MH1, W+OFF_XCA, W+OFF_FEAT, W+OFF_RES);

    // covariance metric + classifier
    covmu_k<<<dim3(5,64),256,0,stream>>>(W+OFF_RES, W+OFF_MU);
    cov_k<<<dim3(5,4),256,0,stream>>>(W+OFF_RES, W+OFF_MU, W+OFF_COV);
    qn_k<<<dim3(64,64),64,0,stream>>>(W+OFF_RES, W+OFF_QN);
    sim_k<<<dim3(64,4),256,0,stream>>>(W+OFF_QN, W+OFF_COV, W+OFF_SIM);
    cls_k<<<64,256,0,stream>>>(W+OFF_SIM, IN[30], OUT);
}

// Round 4
// 757.219 us; speedup vs baseline: 1.4485x; 1.0804x over previous
//
#include <hip/hip_runtime.h>
#include <hip/hip_bf16.h>

__device__ __forceinline__ float lrelu(float x){ return x >= 0.f ? x : 0.2f*x; }
__device__ __forceinline__ float sigm(float x){ return 1.f/(1.f+__expf(-x)); }

// ---------------- workspace layout (float offsets) ----------------
static constexpr size_t OFF_X0    = 0;          // 89*4096 = 364544
static constexpr size_t OFF_POS   = 475712;     // 16384  [h][i][d]
static constexpr size_t OFF_WQT   = 492096;     // 12288  [s][c][o]
static constexpr size_t OFF_STATS = 504384;     // 4 stages * 6 groups * 64 ch * {sum,ss} -> {mean,istd}
static constexpr size_t OFF_P1    = 507456;     // 89*64*1024
static constexpr size_t OFF_P2    = 6340160;    // 89*64*256
static constexpr size_t OFF_FEAT  = 7798336;    // 89*64*256
static constexpr size_t OFF_MH1   = 9256512;    // 89*64*256
static constexpr size_t OFF_RES   = 10714688;   // 89*64*256
static constexpr size_t OFF_MU    = 12172864;   // 320
static constexpr size_t OFF_COV   = 12173184;   // 5*64*64
static constexpr size_t OFF_SIM   = 12193664;   // 64*5*256
static constexpr size_t OFF_R1    = 12275584;   // big overlaid region
static constexpr size_t OFF_C1    = OFF_R1;                 // 89*64*4096 (stage 1 only)
static constexpr size_t OFF_C2    = OFF_R1;                 // 89*64*1024 (c1 dead)
static constexpr size_t OFF_C3    = OFF_R1 + 5832704;       // 89*64*256
static constexpr size_t OFF_F3    = OFF_R1 + 7290880;
static constexpr size_t OFF_C4    = OFF_R1 + 8749056;
static constexpr size_t OFF_CKV   = OFF_R1 + 10207232;      // 89*4*256*48 = 4374528 (packed {k,q,v})
static constexpr size_t OFF_MHRAW = OFF_R1 + 14581760;      // 89*64*256
static constexpr size_t OFF_XCA   = OFF_R1 + 16039936;
static constexpr size_t OFF_SFB   = OFF_R1 + 17498112;      // 89*2*256
static constexpr size_t OFF_QN    = OFF_R1 + 17543680;      // 64*64*256

__device__ __forceinline__ int bn_group(int img){ return (img < 64) ? 0 : (1 + (img-64)/5); }

// ---------------- prep: pack inputs + pos + W^T + zero BN-sum area ----------------
__global__ __launch_bounds__(256) void prep_k(const float* __restrict__ in1, const float* __restrict__ in2,
        const float* __restrict__ relh, const float* __restrict__ relw,
        const float* __restrict__ wq, const float* __restrict__ wk, const float* __restrict__ wv,
        float* __restrict__ ws)
{
    int idx = blockIdx.x*256 + threadIdx.x;
    if (idx < 364544) { ws[OFF_X0+idx] = (idx < 262144 ? in1[idx] : in2[idx-262144]); return; }
    idx -= 364544;
    if (idx < 16384) {
        const int h = idx>>12, r = idx&4095, i = r>>4, d = r&15;
        ws[OFF_POS+idx] = relh[h*256 + d*16 + (i&15)] + relw[h*256 + d*16 + (i>>4)];
        return;
    }
    idx -= 16384;
    if (idx < 12288) {
        const int s = idx/4096, r = idx%4096, c = r>>6, o = r&63;
        const float* wp = (s==0)?wq:((s==1)?wk:wv);
        ws[OFF_WQT+idx] = wp[o*64 + c];   // [s][c][o] = W[o][c]
        return;
    }
    idx -= 12288;
    if (idx < 3072) ws[OFF_STATS+idx] = 0.f;   // zero all 4 stages' sum/ss slots
}

// ---------------- direct 3x3 conv, LDS input staging, fused BN-sum epilogue ----------------
template<int H, int W, int CIN, int CH, int OCB, int PT>
__global__ __launch_bounds__(256) void conv3x3_k(const float* __restrict__ in,
                                                 const float* __restrict__ wt,
                                                 float* __restrict__ out,
                                                 float* __restrict__ bnsum)
{
    constexpr int P = W + 1;
    constexpr int PLANE = H * P;
    constexpr int HW = H * W;
    constexpr int PASSES = HW / (256 * PT);
    __shared__ float lds[CH * PLANE];
    __shared__ float red1[256], red2[256];
    const int img = blockIdx.x;
    const int och0 = blockIdx.y * OCB;
    const int t = threadIdx.x;

    float acc[PASSES][OCB][PT];
#pragma unroll
    for (int a=0;a<PASSES;a++)
#pragma unroll
      for (int o=0;o<OCB;o++)
#pragma unroll
        for (int p=0;p<PT;p++) acc[a][o][p]=0.f;

    for (int cc0 = 0; cc0 < CIN; cc0 += CH) {
        __syncthreads();
        for (int idx = t; idx < CH*HW; idx += 256) {
            const int c = idx / HW, p = idx % HW;
            lds[c*PLANE + (p/W)*P + (p%W)] = in[((size_t)img*CIN + cc0 + c)*HW + p];
        }
        __syncthreads();
        for (int c = 0; c < CH; ++c) {
            float wr[OCB][9];
#pragma unroll
            for (int o=0;o<OCB;o++)
#pragma unroll
              for (int k=0;k<9;k++)
                wr[o][k] = wt[((size_t)(och0+o)*CIN + (cc0+c))*9 + k];   // wave-uniform -> s_load
            const float* Lc = lds + c*PLANE;
#pragma unroll
            for (int ps=0; ps<PASSES; ++ps) {
                const int px0 = (ps*256 + t)*PT;
                const int y = px0 / W, x0 = px0 % W;
#pragma unroll
                for (int ky=0; ky<3; ++ky) {
                    const int yy = y + ky - 1;
                    if (yy >= 0 && yy < H) {
                        const float* Lr = Lc + yy*P;
                        float r[PT+2];
                        r[0] = (x0 > 0) ? Lr[x0-1] : 0.f;
#pragma unroll
                        for (int k2=0;k2<PT;k2++) r[k2+1] = Lr[x0+k2];
                        r[PT+1] = (x0+PT < W) ? Lr[x0+PT] : 0.f;
#pragma unroll
                        for (int p=0;p<PT;p++)
#pragma unroll
                          for (int kx=0;kx<3;kx++) {
                              const float v = r[p+kx];
#pragma unroll
                              for (int o=0;o<OCB;o++)
                                  acc[ps][o][p] += v * wr[o][ky*3+kx];
                          }
                    }
                }
            }
        }
    }
#pragma unroll
    for (int ps=0; ps<PASSES; ++ps) {
        const int px0 = (ps*256 + t)*PT;
#pragma unroll
        for (int o=0;o<OCB;o++)
#pragma unroll
          for (int p=0;p<PT;p++)
            out[((size_t)img*64 + och0+o)*HW + px0 + p] = acc[ps][o][p];
    }
    // fused group-BN partial sums: block covers ALL HW pixels of (img, och0..och0+OCB)
    const int g = bn_group(img);
#pragma unroll
    for (int o=0;o<OCB;o++){
        float s=0.f, ss=0.f;
#pragma unroll
        for (int ps=0;ps<PASSES;ps++)
#pragma unroll
          for (int p=0;p<PT;p++){ const float v=acc[ps][o][p]; s+=v; ss+=v*v; }
        __syncthreads();
        red1[t]=s; red2[t]=ss;
        __syncthreads();
        for (int st=128;st>0;st>>=1){ if(t<st){ red1[t]+=red1[t+st]; red2[t]+=red2[t+st]; } __syncthreads(); }
        if (t==0){
            atomicAdd(&bnsum[(g*64 + och0+o)*2],   red1[0]);
            atomicAdd(&bnsum[(g*64 + och0+o)*2+1], red2[0]);
        }
    }
}

// ---------------- finalize BN stats in place: (sum,ss) -> (mean, 1/sqrt(var+eps)) ----------------
__global__ __launch_bounds__(384) void bnfin_k(float* __restrict__ s, int HW)
{
    const int t = threadIdx.x;           // t = g*64 + c, 6 groups
    const int g = t>>6;
    const float n = (float)(((g==0)?64:5) * HW);
    const float sum = s[t*2], ss = s[t*2+1];
    const float m = sum/n;
    const float var = fmaxf(ss/n - m*m, 0.f);
    s[t*2]   = m;
    s[t*2+1] = 1.f/sqrtf(var + 1e-5f);
}

template<int H, int W>
__global__ __launch_bounds__(256) void bnpool_k(const float* __restrict__ in, const float* __restrict__ stats,
                                 const float* __restrict__ gw, const float* __restrict__ bw,
                                 float* __restrict__ out)
{
    const int img = blockIdx.x, c = blockIdx.y, t = threadIdx.x;
    const int g = bn_group(img);
    const float m = stats[(g*64+c)*2], istd = stats[(g*64+c)*2+1];
    const float a = gw[c]*istd;
    const float b = bw[c] - m*a;
    constexpr int W2=W/2, HW=H*W, N2=(H/2)*W2;
    const float* pl = in + ((size_t)img*64 + c)*HW;
    float* po = out + ((size_t)img*64 + c)*N2;
    for (int opx=t; opx<N2; opx+=256) {
        const int oy=opx/W2, ox=opx%W2;
        const float* q = pl + (2*oy)*W + 2*ox;
        const float v0=lrelu(a*q[0]+b), v1=lrelu(a*q[1]+b), v2=lrelu(a*q[W]+b), v3=lrelu(a*q[W+1]+b);
        po[opx] = fmaxf(fmaxf(v0,v1),fmaxf(v2,v3));
    }
}

__global__ __launch_bounds__(256) void bnapply256_k(const float* __restrict__ in, const float* __restrict__ stats,
                                 const float* __restrict__ gw, const float* __restrict__ bw,
                                 float* __restrict__ out)
{
    const int img = blockIdx.x, c = blockIdx.y, t = threadIdx.x;
    const int g = bn_group(img);
    const float m = stats[(g*64+c)*2], istd = stats[(g*64+c)*2+1];
    const float a = gw[c]*istd;
    const float b = bw[c] - m*a;
    const size_t base = ((size_t)img*64 + c)*256;
    out[base+t] = lrelu(a*in[base+t]+b);
}

// ---------------- MHSA: q/k/v projection -> packed ckv[img][h][j][48] = {k_j, q_j, v_j} ----------------
__global__ __launch_bounds__(256) void proj_k(const float* __restrict__ feat, const float* __restrict__ wT,
               const float* __restrict__ bq, const float* __restrict__ bk, const float* __restrict__ bv,
               float* __restrict__ ckv)
{
    __shared__ float xl[64*256];   // 64 KB exactly
    const int img = blockIdx.x, s = blockIdx.y, t = threadIdx.x;
    for (int idx=t; idx<16384; idx+=256) xl[idx] = feat[(size_t)img*16384 + idx];
    const float* bias = (s==0)?bq:((s==1)?bk:bv);
    const int sofs = (s==0)?16:((s==1)?0:32);      // q->16, k->0, v->32 within the 48-float row
    const float* wp = wT + s*4096;      // [c][o]
    const int o0 = (t>>4)*4, i0 = (t&15)*16;
    const int h = o0>>4, d0 = o0&15;
    __syncthreads();
    float acc[4][16];
    float b0[4];
#pragma unroll
    for (int o=0;o<4;o++) b0[o]=bias[o0+o];
#pragma unroll
    for (int o=0;o<4;o++)
#pragma unroll
      for (int i=0;i<16;i++) acc[o][i]=b0[o];
    for (int c=0;c<64;c++){
        const float4 w4 = *(const float4*)(wp + c*64 + o0);
        const float* xr = xl + c*256 + i0;
#pragma unroll
        for (int k=0;k<4;k++){
            const float4 x4 = *(const float4*)(xr + 4*k);
            acc[0][4*k+0]+=w4.x*x4.x; acc[0][4*k+1]+=w4.x*x4.y; acc[0][4*k+2]+=w4.x*x4.z; acc[0][4*k+3]+=w4.x*x4.w;
            acc[1][4*k+0]+=w4.y*x4.x; acc[1][4*k+1]+=w4.y*x4.y; acc[1][4*k+2]+=w4.y*x4.z; acc[1][4*k+3]+=w4.y*x4.w;
            acc[2][4*k+0]+=w4.z*x4.x; acc[2][4*k+1]+=w4.z*x4.y; acc[2][4*k+2]+=w4.z*x4.z; acc[2][4*k+3]+=w4.z*x4.w;
            acc[3][4*k+0]+=w4.w*x4.x; acc[3][4*k+1]+=w4.w*x4.y; acc[3][4*k+2]+=w4.w*x4.z; acc[3][4*k+3]+=w4.w*x4.w;
        }
    }
#pragma unroll
    for (int ii=0;ii<16;ii++){
        const float4 v = make_float4(acc[0][ii],acc[1][ii],acc[2][ii],acc[3][ii]);
        *(float4*)(ckv + (((size_t)img*4 + h)*256 + i0+ii)*48 + sofs + d0) = v;
    }
}

// ---------------- attention: online softmax, j-side via wave-uniform scalar loads, zero LDS ----------------
// score(i,j) = q_i.k_j + pos_i.q_j = concat(q_i,pos_i) . concat(k_j,q_j)   (K=32)
__global__ __launch_bounds__(256) void attn_k(const float* __restrict__ ckv, const float* __restrict__ pos,
                               float* __restrict__ mhraw)
{
    const int img = blockIdx.x, h = blockIdx.y, i = threadIdx.x;
    const size_t jb = (((size_t)img*4 + h)*256)*48;
    float areg[32];
    {
        const float* myrow = ckv + jb + (size_t)i*48;
#pragma unroll
        for (int k=0;k<4;k++) *(float4*)&areg[4*k]    = *(const float4*)(myrow + 16 + 4*k);  // q_i
#pragma unroll
        for (int k=0;k<4;k++) *(float4*)&areg[16+4*k] = *(const float4*)(pos + h*4096 + i*16 + 4*k); // pos_i
    }
    float mrun = -1e30f, l = 0.f;
    float accv[16];
#pragma unroll
    for (int d=0;d<16;d++) accv[d]=0.f;

    for (int j0=0; j0<256; j0+=2){
        const float* r0 = ckv + jb + (size_t)j0*48;      // wave-uniform -> s_load
        const float* r1 = r0 + 48;
        float s0a=0.f, s0b=0.f, s1a=0.f, s1b=0.f;
#pragma unroll
        for (int dd=0; dd<16; ++dd){
            s0a += areg[2*dd]  *r0[2*dd];
            s0b += areg[2*dd+1]*r0[2*dd+1];
            s1a += areg[2*dd]  *r1[2*dd];
            s1b += areg[2*dd+1]*r1[2*dd+1];
        }
        const float s0 = s0a+s0b, s1 = s1a+s1b;
        const float mnew = fmaxf(mrun, fmaxf(s0,s1));
        const float al = __expf(mrun - mnew);
        const float e0 = __expf(s0 - mnew), e1 = __expf(s1 - mnew);
        mrun = mnew;
        l = l*al + e0 + e1;
        const float* v0 = r0 + 32;
        const float* v1 = r1 + 32;
#pragma unroll
        for (int d=0;d<16;d++) accv[d] = accv[d]*al + e0*v0[d] + e1*v1[d];
    }
    const float rl = 1.f/l;
#pragma unroll
    for (int d=0;d<16;d++)
        mhraw[((size_t)img*64 + h*16 + d)*256 + i] = accv[d]*rl;
}

// ---------------- mhsa per-sample norm + ln affine + residual ----------------
__global__ __launch_bounds__(256) void mhnorm_k(const float* __restrict__ mhraw, const float* __restrict__ lng,
                  const float* __restrict__ lnb, const float* __restrict__ feat, float* __restrict__ out)
{
    __shared__ float r1[256], r2[256];
    const int img = blockIdx.x, t = threadIdx.x;
    const float* base = mhraw + (size_t)img*16384;
    float s=0.f, ss=0.f;
    for (int idx=t; idx<16384; idx+=256){ const float v=base[idx]; s+=v; ss+=v*v; }
    r1[t]=s; r2[t]=ss; __syncthreads();
    for (int st=128;st>0;st>>=1){ if(t<st){r1[t]+=r1[t+st]; r2[t]+=r2[t+st];} __syncthreads(); }
    const float m = r1[0]/16384.f;
    const float var = fmaxf(r2[0]/16384.f - m*m, 0.f);
    const float istd = 1.f/sqrtf(var+1e-5f);
    for (int idx=t; idx<16384; idx+=256){
        const float v = (base[idx]-m)*istd*lng[idx] + lnb[idx] + feat[(size_t)img*16384+idx];
        out[(size_t)img*16384+idx]=v;
    }
}

// ---------------- CBAM channel attention + spatial stats ----------------
__global__ __launch_bounds__(256) void cbamchan_k(const float* __restrict__ feat,
        const float* __restrict__ w1, const float* __restrict__ b1,
        const float* __restrict__ w2, const float* __restrict__ b2,
        float* __restrict__ xca, float* __restrict__ sfb)
{
    __shared__ float pa[256], pm[256];
    __shared__ float favg[64], fmx[64], z1s[8], ca[64];
    const int img = blockIdx.x, t = threadIdx.x;
    const float* base = feat + (size_t)img*16384;
    {
        const int c = t>>2, part = t&3;
        const float* p = base + c*256 + part*64;
        float s=0.f, mx=-1e30f;
        for (int k=0;k<64;k++){ const float v=p[k]; s+=v; mx=fmaxf(mx,v); }
        pa[t]=s; pm[t]=mx;
    }
    __syncthreads();
    if (t<64){
        favg[t] = (pa[t*4]+pa[t*4+1]+pa[t*4+2]+pa[t*4+3])/256.f;
        fmx[t]  = fmaxf(fmaxf(pm[t*4],pm[t*4+1]),fmaxf(pm[t*4+2],pm[t*4+3]));
    }
    __syncthreads();
    if (t<8){
        const int which = t>>2, o = t&3;
        const float* f = which? fmx : favg;
        float z = b1[o];
        for (int c=0;c<64;c++) z += w1[o*64+c]*f[c];
        z1s[t] = fmaxf(z, 0.f);
    }
    __syncthreads();
    if (t<64){
        float z = 2.f*b2[t];   // exc(avg)+exc(max) carries 2x cb2
#pragma unroll
        for (int k=0;k<4;k++) z += w2[t*4+k]*(z1s[k]+z1s[4+k]);
        ca[t] = sigm(z);
    }
    __syncthreads();
    {
        const int i = t;
        float s=0.f, mx=-1e30f;
        for (int c=0;c<64;c++){
            const float v = ca[c]*base[c*256+i];
            xca[(size_t)img*16384 + c*256 + i] = v;
            s += v; mx = fmaxf(mx, v);
        }
        sfb[(size_t)img*512 + i]       = s/64.f;
        sfb[(size_t)img*512 + 256 + i] = mx;
    }
}

// ---------------- CBAM spatial 7x7 + final sa_module sum ----------------
__global__ __launch_bounds__(256) void cbamsp_k(const float* __restrict__ sfb,
      const float* __restrict__ sw, const float* __restrict__ sb,
      const float* __restrict__ mh1, const float* __restrict__ xca, const float* __restrict__ feat,
      float* __restrict__ res)
{
    __shared__ float sf[512];
    __shared__ float wl[98];
    const int img = blockIdx.x, t = threadIdx.x;
    for (int idx=t; idx<512; idx+=256) sf[idx] = sfb[(size_t)img*512 + idx];
    if (t<98) wl[t] = sw[t];
    __syncthreads();
    const int i = t, y = i>>4, x = i&15;
    float s = sb[0];
    for (int ch=0; ch<2; ++ch)
      for (int ky=0; ky<7; ++ky){
        const int yy = y+ky-3;
        if (yy<0||yy>=16) continue;
        for (int kx=0; kx<7; ++kx){
            const int xx = x+kx-3;
            if (xx<0||xx>=16) continue;
            s += sf[ch*256 + yy*16 + xx]*wl[ch*49 + ky*7 + kx];
        }
      }
    const float sa = sigm(s);
    const size_t b = (size_t)img*16384;
    for (int c=0;c<64;c++){
        const size_t idx = b + c*256 + i;
        res[idx] = mh1[idx] + sa*xca[idx] + feat[idx];   // mh1 already contains +x
    }
}

// ---------------- covariance ----------------
__global__ __launch_bounds__(256) void covmu_k(const float* __restrict__ res, float* __restrict__ mu)
{
    __shared__ float r1[256];
    const int n = blockIdx.x, c = blockIdx.y, t = threadIdx.x;
    float s=0.f;
    for (int sh=0; sh<5; ++sh)
        s += res[((size_t)(64 + n*5 + sh)*64 + c)*256 + t];
    r1[t]=s; __syncthreads();
    for (int st=128;st>0;st>>=1){ if(t<st) r1[t]+=r1[t+st]; __syncthreads(); }
    if (t==0) mu[n*64+c] = r1[0]/1280.f;
}

__global__ __launch_bounds__(256) void cov_k(const float* __restrict__ res, const float* __restrict__ mu,
                                             float* __restrict__ cov)
{
    __shared__ float Xl[64*129];   // 33 KB
    const int n = blockIdx.x, by = blockIdx.y, t = threadIdx.x;
    const int c = by*16 + (t>>4);
    const int d0 = (t&15)*4;
    float acc[4] = {0.f,0.f,0.f,0.f};
    for (int sh=0; sh<5; ++sh)
      for (int half=0; half<2; ++half){
        __syncthreads();
        for (int idx=t; idx<8192; idx+=256){
            const int ch = idx>>7, p = idx&127;
            Xl[ch*129+p] = res[((size_t)(64+n*5+sh)*64 + ch)*256 + half*128 + p] - mu[n*64+ch];
        }
        __syncthreads();
        for (int p=0;p<128;p++){
            const float xc = Xl[c*129+p];
#pragma unroll
            for (int k=0;k<4;k++) acc[k] += xc*Xl[(d0+k)*129+p];
        }
      }
#pragma unroll
    for (int k=0;k<4;k++) cov[((size_t)n*64 + c)*64 + d0+k] = acc[k]*(1.f/1279.f);
}

// ---------------- Q normalize over hw per (b,c) ----------------
__global__ __launch_bounds__(64) void qn_k(const float* __restrict__ res, float* __restrict__ qn)
{
    const int b = blockIdx.x, c = blockIdx.y, t = threadIdx.x;
    const size_t base = ((size_t)b*64 + c)*256;
    const float4 v = *(const float4*)(res + base + t*4);
    float ss = v.x*v.x + v.y*v.y + v.z*v.z + v.w*v.w;
#pragma unroll
    for (int off=32; off>0; off>>=1) ss += __shfl_xor(ss, off);
    const float inv = 1.f/sqrtf(ss);
    float4 o; o.x=v.x*inv; o.y=v.y*inv; o.z=v.z*inv; o.w=v.w*inv;
    *(float4*)(qn + base + t*4) = o;
}

// ---------------- sim[b,j,i] = Qn(:,i)^T cov_j Qn(:,i) ----------------
__global__ __launch_bounds__(256) void sim_k(const float* __restrict__ qn, const float* __restrict__ cov,
                                             float* __restrict__ sim)
{
    __shared__ float covj[64*65];
    __shared__ float Vl[64*68];
    __shared__ float simred[320];
    const int b = blockIdx.x, iq = blockIdx.y, t = threadIdx.x;
    const int i0g = iq*64;
    for (int idx=t; idx<4096; idx+=256){
        const int c = idx>>6, il = idx&63;
        Vl[c*68+il] = qn[((size_t)b*64+c)*256 + i0g + il];
    }
    for (int idx=t; idx<320; idx+=256) simred[idx]=0.f;
    const int c0 = (t>>4)*4, i0 = (t&15)*4;
    for (int j=0;j<5;j++){
        __syncthreads();
        for (int idx=t; idx<4096; idx+=256)
            covj[(idx>>6)*65 + (idx&63)] = cov[(size_t)j*4096 + idx];
        __syncthreads();
        float pt[4][4];
#pragma unroll
        for (int a=0;a<4;a++)
#pragma unroll
          for (int bb=0;bb<4;bb++) pt[a][bb]=0.f;
        for (int d=0; d<64; ++d){
            const float4 vv = *(const float4*)&Vl[d*68 + i0];
            float cw[4];
#pragma unroll
            for (int cc=0;cc<4;cc++) cw[cc] = covj[(c0+cc)*65 + d];
#pragma unroll
            for (int cc=0;cc<4;cc++){
                pt[cc][0] += cw[cc]*vv.x;
                pt[cc][1] += cw[cc]*vv.y;
                pt[cc][2] += cw[cc]*vv.z;
                pt[cc][3] += cw[cc]*vv.w;
            }
        }
#pragma unroll
        for (int ii=0;ii<4;ii++){
            float s = 0.f;
#pragma unroll
            for (int cc=0;cc<4;cc++) s += pt[cc][ii]*Vl[(c0+cc)*68 + i0+ii];
            atomicAdd(&simred[j*64 + i0 + ii], s);
        }
    }
    __syncthreads();
    for (int idx=t; idx<320; idx+=256){
        const int j = idx>>6, il = idx&63;
        sim[((size_t)b*5 + j)*256 + i0g + il] = simred[idx];
    }
}

// ---------------- classifier ----------------
__global__ __launch_bounds__(256) void cls_k(const float* __restrict__ sim, const float* __restrict__ cw,
                                             float* __restrict__ out)
{
    __shared__ float red[256];
    const int b = blockIdx.x, t = threadIdx.x;
    const float w = cw[t];
    for (int j=0;j<5;j++){
        const float v = sim[((size_t)b*5 + j)*256 + t];
        red[t] = lrelu(v)*w;
        __syncthreads();
        for (int st=128;st>0;st>>=1){ if(t<st) red[t]+=red[t+st]; __syncthreads(); }
        if (t==0) out[b*5+j] = red[0];
        __syncthreads();
    }
}

// ---------------- launch ----------------
extern "C" void kernel_launch(void* const* d_in, const int* in_sizes, int n_in,
                              void* d_out, int out_size, void* d_ws, size_t ws_size,
                              hipStream_t stream)
{
    const float* IN[31];
    for (int i=0;i<31;i++) IN[i] = (const float*)d_in[i];
    float* W = (float*)d_ws;
    float* OUT = (float*)d_out;

    prep_k<<<1548,256,0,stream>>>(IN[0],IN[1],IN[20],IN[21],IN[14],IN[16],IN[18],W);

    // stage 1: conv1(+stats) -> finalize -> BN/lrelu/pool -> p1 [89,64,32,32]
    conv3x3_k<64,64,1,1,4,4><<<dim3(89,16),256,0,stream>>>(W+OFF_X0, IN[2], W+OFF_C1, W+OFF_STATS);
    bnfin_k<<<1,384,0,stream>>>(W+OFF_STATS, 4096);
    bnpool_k<64,64><<<dim3(89,64),256,0,stream>>>(W+OFF_C1, W+OFF_STATS, IN[3], IN[4], W+OFF_P1);

    // stage 2: conv2(+stats) -> finalize -> BN/lrelu/pool -> p2 [89,64,16,16]
    conv3x3_k<32,32,64,8,8,4><<<dim3(89,8),256,0,stream>>>(W+OFF_P1, IN[5], W+OFF_C2, W+OFF_STATS+768);
    bnfin_k<<<1,384,0,stream>>>(W+OFF_STATS+768, 1024);
    bnpool_k<32,32><<<dim3(89,64),256,0,stream>>>(W+OFF_C2, W+OFF_STATS+768, IN[6], IN[7], W+OFF_P2);

    // stage 3: conv3(+stats) -> finalize -> BN/lrelu -> f3
    conv3x3_k<16,16,64,32,8,1><<<dim3(89,8),256,0,stream>>>(W+OFF_P2, IN[8], W+OFF_C3, W+OFF_STATS+1536);
    bnfin_k<<<1,384,0,stream>>>(W+OFF_STATS+1536, 256);
    bnapply256_k<<<dim3(89,64),256,0,stream>>>(W+OFF_C3, W+OFF_STATS+1536, IN[9], IN[10], W+OFF_F3);

    // stage 4: conv4(+stats) -> finalize -> BN/lrelu -> feat
    conv3x3_k<16,16,64,32,8,1><<<dim3(89,8),256,0,stream>>>(W+OFF_F3, IN[11], W+OFF_C4, W+OFF_STATS+2304);
    bnfin_k<<<1,384,0,stream>>>(W+OFF_STATS+2304, 256);
    bnapply256_k<<<dim3(89,64),256,0,stream>>>(W+OFF_C4, W+OFF_STATS+2304, IN[12], IN[13], W+OFF_FEAT);

    // MHSA
    proj_k<<<dim3(89,3),256,0,stream>>>(W+OFF_FEAT, W+OFF_WQT, IN[15], IN[17], IN[19], W+OFF_CKV);
    attn_k<<<dim3(89,4),256,0,stream>>>(W+OFF_CKV, W+OFF_POS, W+OFF_MHRAW);
    mhnorm_k<<<89,256,0,stream>>>(W+OFF_MHRAW, IN[22], IN[23], W+OFF_FEAT, W+OFF_MH1);

    // CBAM + sa_module sum
    cbamchan_k<<<89,256,0,stream>>>(W+OFF_FEAT, IN[24], IN[25], IN[26], IN[27], W+OFF_XCA, W+OFF_SFB);
    cbamsp_k<<<89,256,0,stream>>>(W+OFF_SFB, IN[28], IN[29], W+OFF_MH1, W+OFF_XCA, W+OFF_FEAT, W+OFF_RES);

    // covariance metric + classifier
    covmu_k<<<dim3(5,64),256,0,stream>>>(W+OFF_RES, W+OFF_MU);
    cov_k<<<dim3(5,4),256,0,stream>>>(W+OFF_RES, W+OFF_MU, W+OFF_COV);
    qn_k<<<dim3(64,64),64,0,stream>>>(W+OFF_RES, W+OFF_QN);
    sim_k<<<dim3(64,4),256,0,stream>>>(W+OFF_QN, W+OFF_COV, W+OFF_SIM);
    cls_k<<<64,256,0,stream>>>(W+OFF_SIM, IN[30], OUT);
}

// Round 5
// 753.735 us; speedup vs baseline: 1.4552x; 1.0046x over previous
//
#include <hip/hip_runtime.h>
#include <hip/hip_bf16.h>

__device__ __forceinline__ float lrelu(float x){ return x >= 0.f ? x : 0.2f*x; }
__device__ __forceinline__ float sigm(float x){ return 1.f/(1.f+__expf(-x)); }

// ---------------- workspace layout (float offsets) ----------------
static constexpr size_t OFF_X0    = 0;          // 89*4096 = 364544
static constexpr size_t OFF_POS   = 475712;     // 16384  [h][i][d]
static constexpr size_t OFF_WQT   = 492096;     // 12288  [s][c][o]
static constexpr size_t OFF_STATS = 504384;     // 4 stages * 6 groups * 64 ch * {sum,ss} -> {mean,istd}
static constexpr size_t OFF_P1    = 507456;     // 89*64*1024
static constexpr size_t OFF_P2    = 6340160;    // 89*64*256
static constexpr size_t OFF_FEAT  = 7798336;    // 89*64*256
static constexpr size_t OFF_MH1   = 9256512;    // 89*64*256
static constexpr size_t OFF_RES   = 10714688;   // 89*64*256
static constexpr size_t OFF_MU    = 12172864;   // 320
static constexpr size_t OFF_COV   = 12173184;   // 5*64*64
static constexpr size_t OFF_SIM   = 12193664;   // 64*5*256
static constexpr size_t OFF_R1    = 12275584;   // big overlaid region
static constexpr size_t OFF_C2    = OFF_R1;                 // 89*64*1024
static constexpr size_t OFF_C3    = OFF_R1 + 5832704;       // 89*64*256
static constexpr size_t OFF_F3    = OFF_R1 + 7290880;
static constexpr size_t OFF_C4    = OFF_R1 + 8749056;
static constexpr size_t OFF_CKV   = OFF_R1 + 10207232;      // 89*4*256*48 (packed {k,q,v})
static constexpr size_t OFF_MHRAW = OFF_R1 + 14581760;      // 89*64*256
static constexpr size_t OFF_XCA   = OFF_R1 + 16039936;
static constexpr size_t OFF_SFB   = OFF_R1 + 17498112;      // 89*2*256
static constexpr size_t OFF_QN    = OFF_R1 + 17543680;      // 64*64*256

__device__ __forceinline__ int bn_group(int img){ return (img < 64) ? 0 : (1 + (img-64)/5); }

// ---------------- prep: pack inputs + pos + W^T + zero BN-sum area ----------------
__global__ __launch_bounds__(256) void prep_k(const float* __restrict__ in1, const float* __restrict__ in2,
        const float* __restrict__ relh, const float* __restrict__ relw,
        const float* __restrict__ wq, const float* __restrict__ wk, const float* __restrict__ wv,
        float* __restrict__ ws)
{
    int idx = blockIdx.x*256 + threadIdx.x;
    if (idx < 364544) { ws[OFF_X0+idx] = (idx < 262144 ? in1[idx] : in2[idx-262144]); return; }
    idx -= 364544;
    if (idx < 16384) {
        const int h = idx>>12, r = idx&4095, i = r>>4, d = r&15;
        ws[OFF_POS+idx] = relh[h*256 + d*16 + (i&15)] + relw[h*256 + d*16 + (i>>4)];
        return;
    }
    idx -= 16384;
    if (idx < 12288) {
        const int s = idx/4096, r = idx%4096, c = r>>6, o = r&63;
        const float* wp = (s==0)?wq:((s==1)?wk:wv);
        ws[OFF_WQT+idx] = wp[o*64 + c];   // [s][c][o] = W[o][c]
        return;
    }
    idx -= 12288;
    if (idx < 3072) ws[OFF_STATS+idx] = 0.f;   // zero all 4 stages' sum/ss slots
}

// ---------------- direct 3x3 conv, LDS input staging, fused BN-sum epilogue ----------------
// STORE=false: stats-only pass (no output write) — used for stage 1 where the
// pre-BN tensor is recomputed by bnpoolconv1_k instead of materialized (saves 186 MB traffic).
template<int H, int W, int CIN, int CH, int OCB, int PT, bool STORE>
__global__ __launch_bounds__(256) void conv3x3_k(const float* __restrict__ in,
                                                 const float* __restrict__ wt,
                                                 float* __restrict__ out,
                                                 float* __restrict__ bnsum)
{
    constexpr int P = W + 1;
    constexpr int PLANE = H * P;
    constexpr int HW = H * W;
    constexpr int PASSES = HW / (256 * PT);
    __shared__ float lds[CH * PLANE];
    __shared__ float red1[256], red2[256];
    const int img = blockIdx.x;
    const int och0 = blockIdx.y * OCB;
    const int t = threadIdx.x;

    float acc[PASSES][OCB][PT];
#pragma unroll
    for (int a=0;a<PASSES;a++)
#pragma unroll
      for (int o=0;o<OCB;o++)
#pragma unroll
        for (int p=0;p<PT;p++) acc[a][o][p]=0.f;

    for (int cc0 = 0; cc0 < CIN; cc0 += CH) {
        __syncthreads();
        for (int idx = t; idx < CH*HW; idx += 256) {
            const int c = idx / HW, p = idx % HW;
            lds[c*PLANE + (p/W)*P + (p%W)] = in[((size_t)img*CIN + cc0 + c)*HW + p];
        }
        __syncthreads();
        for (int c = 0; c < CH; ++c) {
            float wr[OCB][9];
#pragma unroll
            for (int o=0;o<OCB;o++)
#pragma unroll
              for (int k=0;k<9;k++)
                wr[o][k] = wt[((size_t)(och0+o)*CIN + (cc0+c))*9 + k];   // wave-uniform -> s_load
            const float* Lc = lds + c*PLANE;
#pragma unroll
            for (int ps=0; ps<PASSES; ++ps) {
                const int px0 = (ps*256 + t)*PT;
                const int y = px0 / W, x0 = px0 % W;
#pragma unroll
                for (int ky=0; ky<3; ++ky) {
                    const int yy = y + ky - 1;
                    if (yy >= 0 && yy < H) {
                        const float* Lr = Lc + yy*P;
                        float r[PT+2];
                        r[0] = (x0 > 0) ? Lr[x0-1] : 0.f;
#pragma unroll
                        for (int k2=0;k2<PT;k2++) r[k2+1] = Lr[x0+k2];
                        r[PT+1] = (x0+PT < W) ? Lr[x0+PT] : 0.f;
#pragma unroll
                        for (int p=0;p<PT;p++)
#pragma unroll
                          for (int kx=0;kx<3;kx++) {
                              const float v = r[p+kx];
#pragma unroll
                              for (int o=0;o<OCB;o++)
                                  acc[ps][o][p] += v * wr[o][ky*3+kx];
                          }
                    }
                }
            }
        }
    }
    if constexpr (STORE) {
#pragma unroll
        for (int ps=0; ps<PASSES; ++ps) {
            const int px0 = (ps*256 + t)*PT;
#pragma unroll
            for (int o=0;o<OCB;o++)
#pragma unroll
              for (int p=0;p<PT;p++)
                out[((size_t)img*64 + och0+o)*HW + px0 + p] = acc[ps][o][p];
        }
    }
    // fused group-BN partial sums: block covers ALL HW pixels of (img, och0..och0+OCB)
    const int g = bn_group(img);
#pragma unroll
    for (int o=0;o<OCB;o++){
        float s=0.f, ss=0.f;
#pragma unroll
        for (int ps=0;ps<PASSES;ps++)
#pragma unroll
          for (int p=0;p<PT;p++){ const float v=acc[ps][o][p]; s+=v; ss+=v*v; }
        __syncthreads();
        red1[t]=s; red2[t]=ss;
        __syncthreads();
        for (int st=128;st>0;st>>=1){ if(t<st){ red1[t]+=red1[t+st]; red2[t]+=red2[t+st]; } __syncthreads(); }
        if (t==0){
            atomicAdd(&bnsum[(g*64 + och0+o)*2],   red1[0]);
            atomicAdd(&bnsum[(g*64 + och0+o)*2+1], red2[0]);
        }
    }
}

// ---------------- finalize BN stats in place: (sum,ss) -> (mean, 1/sqrt(var+eps)) ----------------
__global__ __launch_bounds__(384) void bnfin_k(float* __restrict__ s, int HW)
{
    const int t = threadIdx.x;           // t = g*64 + c, 6 groups
    const int g = t>>6;
    const float n = (float)(((g==0)?64:5) * HW);
    const float sum = s[t*2], ss = s[t*2+1];
    const float m = sum/n;
    const float var = fmaxf(ss/n - m*m, 0.f);
    s[t*2]   = m;
    s[t*2+1] = 1.f/sqrtf(var + 1e-5f);
}

// ---------------- stage 1 fused: recompute conv1 + BN + lrelu + 2x2 maxpool -> P1 ----------------
__global__ __launch_bounds__(256) void bnpoolconv1_k(const float* __restrict__ x0,
        const float* __restrict__ cw, const float* __restrict__ stats,
        const float* __restrict__ gw, const float* __restrict__ bw,
        float* __restrict__ out)   // [89][64][32][32]
{
    __shared__ float xl[64*65];  // 16.6 KB
    const int img = blockIdx.x, och = blockIdx.y, t = threadIdx.x;
    const float* xp = x0 + (size_t)img*4096;
    for (int idx=t; idx<4096; idx+=256) xl[(idx>>6)*65 + (idx&63)] = xp[idx];
    float w[9];
#pragma unroll
    for (int k=0;k<9;k++) w[k] = cw[och*9+k];   // wave-uniform -> s_load
    const int g = bn_group(img);
    const float m = stats[(g*64+och)*2], istd = stats[(g*64+och)*2+1];
    const float a = gw[och]*istd;
    const float b = bw[och] - m*a;
    __syncthreads();
    const int oy = t>>3, ox0 = (t&7)*4;       // 32 rows x 8 groups of 4 output cols
    float r[4][10];
#pragma unroll
    for (int rr=0; rr<4; ++rr){
        const int yy = 2*oy-1+rr;
#pragma unroll
        for (int cc=0; cc<10; ++cc){
            const int xx = 2*ox0-1+cc;
            r[rr][cc] = (yy>=0 && yy<64 && xx>=0 && xx<64) ? xl[yy*65+xx] : 0.f;
        }
    }
    float4 res;
    float* rp = (float*)&res;
#pragma unroll
    for (int p=0;p<4;p++){
        float best = -1e30f;
#pragma unroll
        for (int sy=0; sy<2; ++sy)
#pragma unroll
          for (int sx=0; sx<2; ++sx){
            float s=0.f;
#pragma unroll
            for (int ky=0;ky<3;ky++)
#pragma unroll
              for (int kx=0;kx<3;kx++)
                s += r[sy+ky][2*p+sx+kx]*w[ky*3+kx];
            best = fmaxf(best, lrelu(a*s+b));
          }
        rp[p] = best;
    }
    *(float4*)(out + ((size_t)img*64+och)*1024 + oy*32 + ox0) = res;
}

template<int H, int W>
__global__ __launch_bounds__(256) void bnpool_k(const float* __restrict__ in, const float* __restrict__ stats,
                                 const float* __restrict__ gw, const float* __restrict__ bw,
                                 float* __restrict__ out)
{
    const int img = blockIdx.x, c = blockIdx.y, t = threadIdx.x;
    const int g = bn_group(img);
    const float m = stats[(g*64+c)*2], istd = stats[(g*64+c)*2+1];
    const float a = gw[c]*istd;
    const float b = bw[c] - m*a;
    constexpr int W2=W/2, HW=H*W, N2=(H/2)*W2;
    const float* pl = in + ((size_t)img*64 + c)*HW;
    float* po = out + ((size_t)img*64 + c)*N2;
    for (int opx=t; opx<N2; opx+=256) {
        const int oy=opx/W2, ox=opx%W2;
        const float* q = pl + (2*oy)*W + 2*ox;
        const float v0=lrelu(a*q[0]+b), v1=lrelu(a*q[1]+b), v2=lrelu(a*q[W]+b), v3=lrelu(a*q[W+1]+b);
        po[opx] = fmaxf(fmaxf(v0,v1),fmaxf(v2,v3));
    }
}

__global__ __launch_bounds__(256) void bnapply256_k(const float* __restrict__ in, const float* __restrict__ stats,
                                 const float* __restrict__ gw, const float* __restrict__ bw,
                                 float* __restrict__ out)
{
    const int img = blockIdx.x, c = blockIdx.y, t = threadIdx.x;
    const int g = bn_group(img);
    const float m = stats[(g*64+c)*2], istd = stats[(g*64+c)*2+1];
    const float a = gw[c]*istd;
    const float b = bw[c] - m*a;
    const size_t base = ((size_t)img*64 + c)*256;
    out[base+t] = lrelu(a*in[base+t]+b);
}

// ---------------- MHSA: q/k/v projection -> packed ckv[img][h][j][48] = {k_j, q_j, v_j} ----------------
__global__ __launch_bounds__(256) void proj_k(const float* __restrict__ feat, const float* __restrict__ wT,
               const float* __restrict__ bq, const float* __restrict__ bk, const float* __restrict__ bv,
               float* __restrict__ ckv)
{
    __shared__ float xl[64*256];   // 64 KB exactly
    const int img = blockIdx.x, s = blockIdx.y, t = threadIdx.x;
    for (int idx=t; idx<16384; idx+=256) xl[idx] = feat[(size_t)img*16384 + idx];
    const float* bias = (s==0)?bq:((s==1)?bk:bv);
    const int sofs = (s==0)?16:((s==1)?0:32);      // q->16, k->0, v->32 within the 48-float row
    const float* wp = wT + s*4096;      // [c][o]
    const int o0 = (t>>4)*4, i0 = (t&15)*16;
    const int h = o0>>4, d0 = o0&15;
    __syncthreads();
    float acc[4][16];
    float b0[4];
#pragma unroll
    for (int o=0;o<4;o++) b0[o]=bias[o0+o];
#pragma unroll
    for (int o=0;o<4;o++)
#pragma unroll
      for (int i=0;i<16;i++) acc[o][i]=b0[o];
    for (int c=0;c<64;c++){
        const float4 w4 = *(const float4*)(wp + c*64 + o0);
        const float* xr = xl + c*256 + i0;
#pragma unroll
        for (int k=0;k<4;k++){
            const float4 x4 = *(const float4*)(xr + 4*k);
            acc[0][4*k+0]+=w4.x*x4.x; acc[0][4*k+1]+=w4.x*x4.y; acc[0][4*k+2]+=w4.x*x4.z; acc[0][4*k+3]+=w4.x*x4.w;
            acc[1][4*k+0]+=w4.y*x4.x; acc[1][4*k+1]+=w4.y*x4.y; acc[1][4*k+2]+=w4.y*x4.z; acc[1][4*k+3]+=w4.y*x4.w;
            acc[2][4*k+0]+=w4.z*x4.x; acc[2][4*k+1]+=w4.z*x4.y; acc[2][4*k+2]+=w4.z*x4.z; acc[2][4*k+3]+=w4.z*x4.w;
            acc[3][4*k+0]+=w4.w*x4.x; acc[3][4*k+1]+=w4.w*x4.y; acc[3][4*k+2]+=w4.w*x4.z; acc[3][4*k+3]+=w4.w*x4.w;
        }
    }
#pragma unroll
    for (int ii=0;ii<16;ii++){
        const float4 v = make_float4(acc[0][ii],acc[1][ii],acc[2][ii],acc[3][ii]);
        *(float4*)(ckv + (((size_t)img*4 + h)*256 + i0+ii)*48 + sofs + d0) = v;
    }
}

// ---------------- attention: online softmax, j-side via wave-uniform scalar loads, zero LDS ----------------
__global__ __launch_bounds__(256) void attn_k(const float* __restrict__ ckv, const float* __restrict__ pos,
                               float* __restrict__ mhraw)
{
    const int img = blockIdx.x, h = blockIdx.y, i = threadIdx.x;
    const size_t jb = (((size_t)img*4 + h)*256)*48;
    float areg[32];
    {
        const float* myrow = ckv + jb + (size_t)i*48;
#pragma unroll
        for (int k=0;k<4;k++) *(float4*)&areg[4*k]    = *(const float4*)(myrow + 16 + 4*k);  // q_i
#pragma unroll
        for (int k=0;k<4;k++) *(float4*)&areg[16+4*k] = *(const float4*)(pos + h*4096 + i*16 + 4*k); // pos_i
    }
    float mrun = -1e30f, l = 0.f;
    float accv[16];
#pragma unroll
    for (int d=0;d<16;d++) accv[d]=0.f;

    for (int j0=0; j0<256; j0+=2){
        const float* r0 = ckv + jb + (size_t)j0*48;      // wave-uniform -> s_load
        const float* r1 = r0 + 48;
        float s0a=0.f, s0b=0.f, s1a=0.f, s1b=0.f;
#pragma unroll
        for (int dd=0; dd<16; ++dd){
            s0a += areg[2*dd]  *r0[2*dd];
            s0b += areg[2*dd+1]*r0[2*dd+1];
            s1a += areg[2*dd]  *r1[2*dd];
            s1b += areg[2*dd+1]*r1[2*dd+1];
        }
        const float s0 = s0a+s0b, s1 = s1a+s1b;
        const float mnew = fmaxf(mrun, fmaxf(s0,s1));
        const float al = __expf(mrun - mnew);
        const float e0 = __expf(s0 - mnew), e1 = __expf(s1 - mnew);
        mrun = mnew;
        l = l*al + e0 + e1;
        const float* v0 = r0 + 32;
        const float* v1 = r1 + 32;
#pragma unroll
        for (int d=0;d<16;d++) accv[d] = accv[d]*al + e0*v0[d] + e1*v1[d];
    }
    const float rl = 1.f/l;
#pragma unroll
    for (int d=0;d<16;d++)
        mhraw[((size_t)img*64 + h*16 + d)*256 + i] = accv[d]*rl;
}

// ---------------- mhsa per-sample norm + ln affine + residual ----------------
__global__ __launch_bounds__(256) void mhnorm_k(const float* __restrict__ mhraw, const float* __restrict__ lng,
                  const float* __restrict__ lnb, const float* __restrict__ feat, float* __restrict__ out)
{
    __shared__ float r1[256], r2[256];
    const int img = blockIdx.x, t = threadIdx.x;
    const float* base = mhraw + (size_t)img*16384;
    float s=0.f, ss=0.f;
    for (int idx=t; idx<16384; idx+=256){ const float v=base[idx]; s+=v; ss+=v*v; }
    r1[t]=s; r2[t]=ss; __syncthreads();
    for (int st=128;st>0;st>>=1){ if(t<st){r1[t]+=r1[t+st]; r2[t]+=r2[t+st];} __syncthreads(); }
    const float m = r1[0]/16384.f;
    const float var = fmaxf(r2[0]/16384.f - m*m, 0.f);
    const float istd = 1.f/sqrtf(var+1e-5f);
    for (int idx=t; idx<16384; idx+=256){
        const float v = (base[idx]-m)*istd*lng[idx] + lnb[idx] + feat[(size_t)img*16384+idx];
        out[(size_t)img*16384+idx]=v;
    }
}

// ---------------- CBAM channel attention + spatial stats ----------------
__global__ __launch_bounds__(256) void cbamchan_k(const float* __restrict__ feat,
        const float* __restrict__ w1, const float* __restrict__ b1,
        const float* __restrict__ w2, const float* __restrict__ b2,
        float* __restrict__ xca, float* __restrict__ sfb)
{
    __shared__ float pa[256], pm[256];
    __shared__ float favg[64], fmx[64], z1s[8], ca[64];
    const int img = blockIdx.x, t = threadIdx.x;
    const float* base = feat + (size_t)img*16384;
    {
        const int c = t>>2, part = t&3;
        const float* p = base + c*256 + part*64;
        float s=0.f, mx=-1e30f;
        for (int k=0;k<64;k++){ const float v=p[k]; s+=v; mx=fmaxf(mx,v); }
        pa[t]=s; pm[t]=mx;
    }
    __syncthreads();
    if (t<64){
        favg[t] = (pa[t*4]+pa[t*4+1]+pa[t*4+2]+pa[t*4+3])/256.f;
        fmx[t]  = fmaxf(fmaxf(pm[t*4],pm[t*4+1]),fmaxf(pm[t*4+2],pm[t*4+3]));
    }
    __syncthreads();
    if (t<8){
        const int which = t>>2, o = t&3;
        const float* f = which? fmx : favg;
        float z = b1[o];
        for (int c=0;c<64;c++) z += w1[o*64+c]*f[c];
        z1s[t] = fmaxf(z, 0.f);
    }
    __syncthreads();
    if (t<64){
        float z = 2.f*b2[t];   // exc(avg)+exc(max) carries 2x cb2
#pragma unroll
        for (int k=0;k<4;k++) z += w2[t*4+k]*(z1s[k]+z1s[4+k]);
        ca[t] = sigm(z);
    }
    __syncthreads();
    {
        const int i = t;
        float s=0.f, mx=-1e30f;
        for (int c=0;c<64;c++){
            const float v = ca[c]*base[c*256+i];
            xca[(size_t)img*16384 + c*256 + i] = v;
            s += v; mx = fmaxf(mx, v);
        }
        sfb[(size_t)img*512 + i]       = s/64.f;
        sfb[(size_t)img*512 + 256 + i] = mx;
    }
}

// ---------------- CBAM spatial 7x7 + final sa_module sum ----------------
__global__ __launch_bounds__(256) void cbamsp_k(const float* __restrict__ sfb,
      const float* __restrict__ sw, const float* __restrict__ sb,
      const float* __restrict__ mh1, const float* __restrict__ xca, const float* __restrict__ feat,
      float* __restrict__ res)
{
    __shared__ float sf[512];
    __shared__ float wl[98];
    const int img = blockIdx.x, t = threadIdx.x;
    for (int idx=t; idx<512; idx+=256) sf[idx] = sfb[(size_t)img*512 + idx];
    if (t<98) wl[t] = sw[t];
    __syncthreads();
    const int i = t, y = i>>4, x = i&15;
    float s = sb[0];
    for (int ch=0; ch<2; ++ch)
      for (int ky=0; ky<7; ++ky){
        const int yy = y+ky-3;
        if (yy<0||yy>=16) continue;
        for (int kx=0; kx<7; ++kx){
            const int xx = x+kx-3;
            if (xx<0||xx>=16) continue;
            s += sf[ch*256 + yy*16 + xx]*wl[ch*49 + ky*7 + kx];
        }
      }
    const float sa = sigm(s);
    const size_t b = (size_t)img*16384;
    for (int c=0;c<64;c++){
        const size_t idx = b + c*256 + i;
        res[idx] = mh1[idx] + sa*xca[idx] + feat[idx];   // mh1 already contains +x
    }
}

// ---------------- covariance ----------------
__global__ __launch_bounds__(256) void covmu_k(const float* __restrict__ res, float* __restrict__ mu)
{
    __shared__ float r1[256];
    const int n = blockIdx.x, c = blockIdx.y, t = threadIdx.x;
    float s=0.f;
    for (int sh=0; sh<5; ++sh)
        s += res[((size_t)(64 + n*5 + sh)*64 + c)*256 + t];
    r1[t]=s; __syncthreads();
    for (int st=128;st>0;st>>=1){ if(t<st) r1[t]+=r1[t+st]; __syncthreads(); }
    if (t==0) mu[n*64+c] = r1[0]/1280.f;
}

__global__ __launch_bounds__(256) void cov_k(const float* __restrict__ res, const float* __restrict__ mu,
                                             float* __restrict__ cov)
{
    __shared__ float Xl[64*129];   // 33 KB
    const int n = blockIdx.x, by = blockIdx.y, t = threadIdx.x;
    const int c = by*16 + (t>>4);
    const int d0 = (t&15)*4;
    float acc[4] = {0.f,0.f,0.f,0.f};
    for (int sh=0; sh<5; ++sh)
      for (int half=0; half<2; ++half){
        __syncthreads();
        for (int idx=t; idx<8192; idx+=256){
            const int ch = idx>>7, p = idx&127;
            Xl[ch*129+p] = res[((size_t)(64+n*5+sh)*64 + ch)*256 + half*128 + p] - mu[n*64+ch];
        }
        __syncthreads();
        for (int p=0;p<128;p++){
            const float xc = Xl[c*129+p];
#pragma unroll
            for (int k=0;k<4;k++) acc[k] += xc*Xl[(d0+k)*129+p];
        }
      }
#pragma unroll
    for (int k=0;k<4;k++) cov[((size_t)n*64 + c)*64 + d0+k] = acc[k]*(1.f/1279.f);
}

// ---------------- Q normalize over hw per (b,c) ----------------
__global__ __launch_bounds__(64) void qn_k(const float* __restrict__ res, float* __restrict__ qn)
{
    const int b = blockIdx.x, c = blockIdx.y, t = threadIdx.x;
    const size_t base = ((size_t)b*64 + c)*256;
    const float4 v = *(const float4*)(res + base + t*4);
    float ss = v.x*v.x + v.y*v.y + v.z*v.z + v.w*v.w;
#pragma unroll
    for (int off=32; off>0; off>>=1) ss += __shfl_xor(ss, off);
    const float inv = 1.f/sqrtf(ss);
    float4 o; o.x=v.x*inv; o.y=v.y*inv; o.z=v.z*inv; o.w=v.w*inv;
    *(float4*)(qn + base + t*4) = o;
}

// ---------------- sim[b,j,i] = Qn(:,i)^T cov_j Qn(:,i) ----------------
__global__ __launch_bounds__(256) void sim_k(const float* __restrict__ qn, const float* __restrict__ cov,
                                             float* __restrict__ sim)
{
    __shared__ float covj[64*65];
    __shared__ float Vl[64*68];
    __shared__ float simred[320];
    const int b = blockIdx.x, iq = blockIdx.y, t = threadIdx.x;
    const int i0g = iq*64;
    for (int idx=t; idx<4096; idx+=256){
        const int c = idx>>6, il = idx&63;
        Vl[c*68+il] = qn[((size_t)b*64+c)*256 + i0g + il];
    }
    for (int idx=t; idx<320; idx+=256) simred[idx]=0.f;
    const int c0 = (t>>4)*4, i0 = (t&15)*4;
    for (int j=0;j<5;j++){
        __syncthreads();
        for (int idx=t; idx<4096; idx+=256)
            covj[(idx>>6)*65 + (idx&63)] = cov[(size_t)j*4096 + idx];
        __syncthreads();
        float pt[4][4];
#pragma unroll
        for (int a=0;a<4;a++)
#pragma unroll
          for (int bb=0;bb<4;bb++) pt[a][bb]=0.f;
        for (int d=0; d<64; ++d){
            const float4 vv = *(const float4*)&Vl[d*68 + i0];
            float cw[4];
#pragma unroll
            for (int cc=0;cc<4;cc++) cw[cc] = covj[(c0+cc)*65 + d];
#pragma unroll
            for (int cc=0;cc<4;cc++){
                pt[cc][0] += cw[cc]*vv.x;
                pt[cc][1] += cw[cc]*vv.y;
                pt[cc][2] += cw[cc]*vv.z;
                pt[cc][3] += cw[cc]*vv.w;
            }
        }
#pragma unroll
        for (int ii=0;ii<4;ii++){
            float s = 0.f;
#pragma unroll
            for (int cc=0;cc<4;cc++) s += pt[cc][ii]*Vl[(c0+cc)*68 + i0+ii];
            atomicAdd(&simred[j*64 + i0 + ii], s);
        }
    }
    __syncthreads();
    for (int idx=t; idx<320; idx+=256){
        const int j = idx>>6, il = idx&63;
        sim[((size_t)b*5 + j)*256 + i0g + il] = simred[idx];
    }
}

// ---------------- classifier ----------------
__global__ __launch_bounds__(256) void cls_k(const float* __restrict__ sim, const float* __restrict__ cw,
                                             float* __restrict__ out)
{
    __shared__ float red[256];
    const int b = blockIdx.x, t = threadIdx.x;
    const float w = cw[t];
    for (int j=0;j<5;j++){
        const float v = sim[((size_t)b*5 + j)*256 + t];
        red[t] = lrelu(v)*w;
        __syncthreads();
        for (int st=128;st>0;st>>=1){ if(t<st) red[t]+=red[t+st]; __syncthreads(); }
        if (t==0) out[b*5+j] = red[0];
        __syncthreads();
    }
}

// ---------------- launch ----------------
extern "C" void kernel_launch(void* const* d_in, const int* in_sizes, int n_in,
                              void* d_out, int out_size, void* d_ws, size_t ws_size,
                              hipStream_t stream)
{
    const float* IN[31];
    for (int i=0;i<31;i++) IN[i] = (const float*)d_in[i];
    float* W = (float*)d_ws;
    float* OUT = (float*)d_out;

    prep_k<<<1548,256,0,stream>>>(IN[0],IN[1],IN[20],IN[21],IN[14],IN[16],IN[18],W);

    // stage 1: conv1 stats-only (no 93 MB materialization) -> finalize -> fused recompute+BN+pool
    conv3x3_k<64,64,1,1,4,4,false><<<dim3(89,16),256,0,stream>>>(W+OFF_X0, IN[2], nullptr, W+OFF_STATS);
    bnfin_k<<<1,384,0,stream>>>(W+OFF_STATS, 4096);
    bnpoolconv1_k<<<dim3(89,64),256,0,stream>>>(W+OFF_X0, IN[2], W+OFF_STATS, IN[3], IN[4], W+OFF_P1);

    // stage 2: conv2(+stats) -> finalize -> BN/lrelu/pool -> p2 [89,64,16,16]
    conv3x3_k<32,32,64,8,8,4,true><<<dim3(89,8),256,0,stream>>>(W+OFF_P1, IN[5], W+OFF_C2, W+OFF_STATS+768);
    bnfin_k<<<1,384,0,stream>>>(W+OFF_STATS+768, 1024);
    bnpool_k<32,32><<<dim3(89,64),256,0,stream>>>(W+OFF_C2, W+OFF_STATS+768, IN[6], IN[7], W+OFF_P2);

    // stage 3: conv3(+stats) -> finalize -> BN/lrelu -> f3
    conv3x3_k<16,16,64,32,8,1,true><<<dim3(89,8),256,0,stream>>>(W+OFF_P2, IN[8], W+OFF_C3, W+OFF_STATS+1536);
    bnfin_k<<<1,384,0,stream>>>(W+OFF_STATS+1536, 256);
    bnapply256_k<<<dim3(89,64),256,0,stream>>>(W+OFF_C3, W+OFF_STATS+1536, IN[9], IN[10], W+OFF_F3);

    // stage 4: conv4(+stats) -> finalize -> BN/lrelu -> feat
    conv3x3_k<16,16,64,32,8,1,true><<<dim3(89,8),256,0,stream>>>(W+OFF_F3, IN[11], W+OFF_C4, W+OFF_STATS+2304);
    bnfin_k<<<1,384,0,stream>>>(W+OFF_STATS+2304, 256);
    bnapply256_k<<<dim3(89,64),256,0,stream>>>(W+OFF_C4, W+OFF_STATS+2304, IN[12], IN[13], W+OFF_FEAT);

    // MHSA
    proj_k<<<dim3(89,3),256,0,stream>>>(W+OFF_FEAT, W+OFF_WQT, IN[15], IN[17], IN[19], W+OFF_CKV);
    attn_k<<<dim3(89,4),256,0,stream>>>(W+OFF_CKV, W+OFF_POS, W+OFF_MHRAW);
    mhnorm_k<<<89,256,0,stream>>>(W+OFF_MHRAW, IN[22], IN[23], W+OFF_FEAT, W+OFF_MH1);

    // CBAM + sa_module sum
    cbamchan_k<<<89,256,0,stream>>>(W+OFF_FEAT, IN[24], IN[25], IN[26], IN[27], W+OFF_XCA, W+OFF_SFB);
    cbamsp_k<<<89,256,0,stream>>>(W+OFF_SFB, IN[28], IN[29], W+OFF_MH1, W+OFF_XCA, W+OFF_FEAT, W+OFF_RES);

    // covariance metric + classifier
    covmu_k<<<dim3(5,64),256,0,stream>>>(W+OFF_RES, W+OFF_MU);
    cov_k<<<dim3(5,4),256,0,stream>>>(W+OFF_RES, W+OFF_MU, W+OFF_COV);
    qn_k<<<dim3(64,64),64,0,stream>>>(W+OFF_RES, W+OFF_QN);
    sim_k<<<dim3(64,4),256,0,stream>>>(W+OFF_QN, W+OFF_COV, W+OFF_SIM);
    cls_k<<<64,256,0,stream>>>(W+OFF_SIM, IN[30], OUT);
}